// Round 1
// baseline (687.529 us; speedup 1.0000x reference)
//
#include <hip/hip_runtime.h>

#define F_IN 512
#define HDIM 64
#define NCLS 40
#define NLAYER 4
#define EPS_F 0.2f

__device__ __forceinline__ float wsum(float v) {
#pragma unroll
  for (int off = 32; off > 0; off >>= 1) v += __shfl_xor(v, off, 64);
  return v;
}
__device__ __forceinline__ float wmax(float v) {
#pragma unroll
  for (int off = 32; off > 0; off >>= 1) v = fmaxf(v, __shfl_xor(v, off, 64));
  return v;
}

// ---------------- CSR build ----------------
__global__ __launch_bounds__(256) void k_init_n(int* indeg, int* fill, int nN) {
  int i = blockIdx.x * 256 + threadIdx.x;
  if (i < nN) { indeg[i] = 0; fill[i] = 0; }
}

__global__ __launch_bounds__(256) void k_hist(const int* __restrict__ dst, int* indeg, int nE) {
  int e = blockIdx.x * 256 + threadIdx.x;
  if (e < nE) atomicAdd(&indeg[dst[e]], 1);
}

__global__ __launch_bounds__(256) void k_dinv(const int* __restrict__ indeg, float* dinv, int nN) {
  int i = blockIdx.x * 256 + threadIdx.x;
  if (i < nN) dinv[i] = rsqrtf((float)indeg[i] + 1.0f);  // +1 self-loop
}

// per-512-chunk sums
__global__ __launch_bounds__(256) void k_bsum(const int* __restrict__ indeg, int* bsum, int nN) {
  int i0 = blockIdx.x * 512 + threadIdx.x;
  int v = 0;
  if (i0 < nN) v += indeg[i0];
  if (i0 + 256 < nN) v += indeg[i0 + 256];
#pragma unroll
  for (int off = 32; off > 0; off >>= 1) v += __shfl_xor(v, off, 64);
  __shared__ int s[4];
  if ((threadIdx.x & 63) == 0) s[threadIdx.x >> 6] = v;
  __syncthreads();
  if (threadIdx.x == 0) bsum[blockIdx.x] = s[0] + s[1] + s[2] + s[3];
}

// exclusive scan of <=128 block sums (single block)
__global__ __launch_bounds__(128) void k_bscan(const int* __restrict__ bsum, int* bpre,
                                               int* rowptr, int nblk, int nN, int nE) {
  __shared__ int sb[128];
  int t = threadIdx.x;
  int v = (t < nblk) ? bsum[t] : 0;
  sb[t] = v;
  __syncthreads();
  int acc = v;
  for (int off = 1; off < 128; off <<= 1) {
    int o = (t >= off) ? sb[t - off] : 0;
    __syncthreads();
    acc += o;
    sb[t] = acc;
    __syncthreads();
  }
  if (t < nblk) bpre[t] = acc - v;
  if (t == 0) rowptr[nN] = nE;
}

// per-chunk exclusive scan -> rowptr
__global__ __launch_bounds__(512) void k_rowptr(const int* __restrict__ indeg,
                                                const int* __restrict__ bpre, int* rowptr, int nN) {
  __shared__ int sb[512];
  int t = threadIdx.x;
  int i = blockIdx.x * 512 + t;
  int v = (i < nN) ? indeg[i] : 0;
  sb[t] = v;
  __syncthreads();
  int acc = v;
  for (int off = 1; off < 512; off <<= 1) {
    int o = (t >= off) ? sb[t - off] : 0;
    __syncthreads();
    acc += o;
    sb[t] = acc;
    __syncthreads();
  }
  if (i < nN) rowptr[i] = bpre[blockIdx.x] + acc - v;
}

__global__ __launch_bounds__(256) void k_scatter(const int* __restrict__ src,
                                                 const int* __restrict__ dst,
                                                 const int* __restrict__ rowptr, int* fill,
                                                 int* csrsrc, int nE) {
  int e = blockIdx.x * 256 + threadIdx.x;
  if (e < nE) {
    int d = dst[e];
    int p = atomicAdd(&fill[d], 1);
    csrsrc[rowptr[d] + p] = src[e];
  }
}

// ---------------- lin1: h = relu(x @ W1^T + b1), 64x64 output tile ----------------
__global__ __launch_bounds__(256) void k_lin1(const float* __restrict__ x,
                                              const float* __restrict__ W1,
                                              const float* __restrict__ b1,
                                              float* __restrict__ out, int nN) {
  __shared__ float xs[64][33];  // [node][kk], padded -> conflict-free scalar reads
  __shared__ float ws[32][64];  // [kk][j], float4-readable
  const int tid = threadIdx.x;
  const int n0 = blockIdx.x * 64;
  const int ng = tid >> 4;         // 0..15
  const int fc = (tid & 15) << 2;  // 0,4,...,60
  const int nr = ng << 2;          // 0,4,...,60
  float acc[4][4] = {{0.f, 0.f, 0.f, 0.f},
                     {0.f, 0.f, 0.f, 0.f},
                     {0.f, 0.f, 0.f, 0.f},
                     {0.f, 0.f, 0.f, 0.f}};
  const int ld_row = tid >> 3;         // 0..31
  const int ld_kkb = (tid & 7) << 2;   // 0,4,...,28

  for (int k0 = 0; k0 < F_IN; k0 += 32) {
    // stage x tile (transposed into [node][kk])
#pragma unroll
    for (int r = 0; r < 2; ++r) {
      int nl = ld_row + r * 32;
      int n = n0 + nl;
      float4 v = make_float4(0.f, 0.f, 0.f, 0.f);
      if (n < nN) v = *reinterpret_cast<const float4*>(&x[(size_t)n * F_IN + k0 + ld_kkb]);
      xs[nl][ld_kkb + 0] = v.x;
      xs[nl][ld_kkb + 1] = v.y;
      xs[nl][ld_kkb + 2] = v.z;
      xs[nl][ld_kkb + 3] = v.w;
    }
    // stage W1 tile transposed -> ws[kk][j]
#pragma unroll
    for (int r = 0; r < 2; ++r) {
      int j = ld_row + r * 32;
      float4 v = *reinterpret_cast<const float4*>(&W1[(size_t)j * F_IN + k0 + ld_kkb]);
      ws[ld_kkb + 0][j] = v.x;
      ws[ld_kkb + 1][j] = v.y;
      ws[ld_kkb + 2][j] = v.z;
      ws[ld_kkb + 3][j] = v.w;
    }
    __syncthreads();
#pragma unroll
    for (int kk = 0; kk < 32; ++kk) {
      float a0 = xs[nr + 0][kk];
      float a1 = xs[nr + 1][kk];
      float a2 = xs[nr + 2][kk];
      float a3 = xs[nr + 3][kk];
      const float4 b = *reinterpret_cast<const float4*>(&ws[kk][fc]);
      acc[0][0] = fmaf(a0, b.x, acc[0][0]); acc[0][1] = fmaf(a0, b.y, acc[0][1]);
      acc[0][2] = fmaf(a0, b.z, acc[0][2]); acc[0][3] = fmaf(a0, b.w, acc[0][3]);
      acc[1][0] = fmaf(a1, b.x, acc[1][0]); acc[1][1] = fmaf(a1, b.y, acc[1][1]);
      acc[1][2] = fmaf(a1, b.z, acc[1][2]); acc[1][3] = fmaf(a1, b.w, acc[1][3]);
      acc[2][0] = fmaf(a2, b.x, acc[2][0]); acc[2][1] = fmaf(a2, b.y, acc[2][1]);
      acc[2][2] = fmaf(a2, b.z, acc[2][2]); acc[2][3] = fmaf(a2, b.w, acc[2][3]);
      acc[3][0] = fmaf(a3, b.x, acc[3][0]); acc[3][1] = fmaf(a3, b.y, acc[3][1]);
      acc[3][2] = fmaf(a3, b.z, acc[3][2]); acc[3][3] = fmaf(a3, b.w, acc[3][3]);
    }
    __syncthreads();
  }
  const float4 bb = *reinterpret_cast<const float4*>(&b1[fc]);
#pragma unroll
  for (int i = 0; i < 4; ++i) {
    int n = n0 + nr + i;
    if (n < nN) {
      float4 o;
      o.x = fmaxf(acc[i][0] + bb.x, 0.f);
      o.y = fmaxf(acc[i][1] + bb.y, 0.f);
      o.z = fmaxf(acc[i][2] + bb.z, 0.f);
      o.w = fmaxf(acc[i][3] + bb.w, 0.f);
      *reinterpret_cast<float4*>(&out[(size_t)n * HDIM + fc]) = o;
    }
  }
}

// ---------------- per-layer scores ----------------
__global__ __launch_bounds__(256) void k_scores(const float* __restrict__ h,
                                                const float* __restrict__ attl,
                                                const float* __restrict__ attr,
                                                float* __restrict__ al, float* __restrict__ ar,
                                                int nN) {
  int wid = threadIdx.x >> 6, lane = threadIdx.x & 63;
  int n = blockIdx.x * 4 + wid;
  if (n >= nN) return;
  float v = h[(size_t)n * HDIM + lane];
  float sl = wsum(v * attl[lane]);
  float sr = wsum(v * attr[lane]);
  if (lane == 0) {
    al[n] = sl;
    ar[n] = sr;
  }
}

// ---------------- per-layer aggregation: wave per destination node ----------------
__global__ __launch_bounds__(256) void k_aggregate(const float* __restrict__ h,
                                                   const float* __restrict__ raw,
                                                   const int* __restrict__ rowptr,
                                                   const int* __restrict__ csrsrc,
                                                   const float* __restrict__ al,
                                                   const float* __restrict__ ar,
                                                   const float* __restrict__ dinv,
                                                   float* __restrict__ hout, int nN) {
  int wid = threadIdx.x >> 6, lane = threadIdx.x & 63;
  int d = blockIdx.x * 4 + wid;
  if (d >= nN) return;
  float ar_d = ar[d];
  float dv_d = dinv[d];
  size_t base = (size_t)d * HDIM;
  float hd = h[base + lane];
  float self_c = tanhf(al[d] + ar_d) * dv_d * dv_d;
  float acc = EPS_F * raw[base + lane] + hd * self_c;
  int e0 = rowptr[d], e1 = rowptr[d + 1];
  for (int e = e0; e < e1; ++e) {
    int s = csrsrc[e];
    float c = tanhf(al[s] + ar_d) * (dinv[s] * dv_d);
    acc = fmaf(h[(size_t)s * HDIM + lane], c, acc);
  }
  hout[base + lane] = acc;
}

// ---------------- output: logits + log_softmax ----------------
__global__ __launch_bounds__(256) void k_out(const float* __restrict__ h,
                                             const float* __restrict__ W2,
                                             const float* __restrict__ b2,
                                             float* __restrict__ out, int nN) {
  __shared__ float w2t[HDIM][NCLS];  // [j][c]
  for (int i = threadIdx.x; i < HDIM * NCLS; i += 256) {
    int c = i / HDIM, j = i % HDIM;
    w2t[j][c] = W2[i];
  }
  __syncthreads();
  int wid = threadIdx.x >> 6, lane = threadIdx.x & 63;
  int n = blockIdx.x * 4 + wid;
  if (n >= nN) return;
  float hv = h[(size_t)n * HDIM + lane];
  int cidx = (lane < NCLS) ? lane : 0;
  float acc = 0.f;
#pragma unroll
  for (int j = 0; j < HDIM; ++j) {
    float xj = __shfl(hv, j, 64);
    acc = fmaf(xj, w2t[j][cidx], acc);
  }
  float logit = (lane < NCLS) ? (b2[lane] + acc) : -INFINITY;
  float m = wmax(logit);
  float ex = (lane < NCLS) ? expf(logit - m) : 0.f;
  float s = wsum(ex);
  if (lane < NCLS) out[(size_t)n * NCLS + lane] = logit - m - logf(s);
}

extern "C" void kernel_launch(void* const* d_in, const int* in_sizes, int n_in,
                              void* d_out, int out_size, void* d_ws, size_t ws_size,
                              hipStream_t stream) {
  const float* x = (const float*)d_in[0];
  const int* ei = (const int*)d_in[1];
  const float* W1 = (const float*)d_in[2];
  const float* b1 = (const float*)d_in[3];
  const float* W2 = (const float*)d_in[4];
  const float* b2 = (const float*)d_in[5];
  const float* attl = (const float*)d_in[6];
  const float* attr = (const float*)d_in[7];
  float* out = (float*)d_out;

  const int nN = in_sizes[0] / F_IN;
  const int nE = in_sizes[1] / 2;
  const int* src = ei;
  const int* dst = ei + nE;

  char* w = (char*)d_ws;
  size_t off = 0;
  auto alloc = [&](size_t bytes) {
    void* p = (void*)(w + off);
    off = (off + bytes + 255) & ~(size_t)255;
    return p;
  };
  float* raw = (float*)alloc((size_t)nN * HDIM * 4);
  float* hA = (float*)alloc((size_t)nN * HDIM * 4);
  float* hB = (float*)alloc((size_t)nN * HDIM * 4);
  float* al = (float*)alloc((size_t)nN * 4);
  float* ar = (float*)alloc((size_t)nN * 4);
  float* dinv = (float*)alloc((size_t)nN * 4);
  int* indeg = (int*)alloc((size_t)nN * 4);
  int* fill = (int*)alloc((size_t)nN * 4);
  int* rowptr = (int*)alloc((size_t)(nN + 1) * 4);
  int* csrsrc = (int*)alloc((size_t)nE * 4);
  int* bsum = (int*)alloc(1024);
  int* bpre = (int*)alloc(1024);

  const int nb_n = (nN + 255) / 256;
  const int nb_e = (nE + 255) / 256;
  const int nblk = (nN + 511) / 512;  // 98 <= 128
  const int nb4 = (nN + 3) / 4;

  k_init_n<<<nb_n, 256, 0, stream>>>(indeg, fill, nN);
  k_hist<<<nb_e, 256, 0, stream>>>(dst, indeg, nE);
  k_dinv<<<nb_n, 256, 0, stream>>>(indeg, dinv, nN);
  k_bsum<<<nblk, 256, 0, stream>>>(indeg, bsum, nN);
  k_bscan<<<1, 128, 0, stream>>>(bsum, bpre, rowptr, nblk, nN, nE);
  k_rowptr<<<nblk, 512, 0, stream>>>(indeg, bpre, rowptr, nN);
  k_scatter<<<nb_e, 256, 0, stream>>>(src, dst, rowptr, fill, csrsrc, nE);
  k_lin1<<<(nN + 63) / 64, 256, 0, stream>>>(x, W1, b1, raw, nN);

  const float* hin = raw;
  float* hout = hA;
  for (int l = 0; l < NLAYER; ++l) {
    k_scores<<<nb4, 256, 0, stream>>>(hin, attl + l * HDIM, attr + l * HDIM, al, ar, nN);
    k_aggregate<<<nb4, 256, 0, stream>>>(hin, raw, rowptr, csrsrc, al, ar, dinv, hout, nN);
    hin = hout;
    hout = (hout == hA) ? hB : hA;
  }
  k_out<<<nb4, 256, 0, stream>>>(hin, W2, b2, out, nN);
}

// Round 2
// 480.610 us; speedup vs baseline: 1.4305x; 1.4305x over previous
//
#include <hip/hip_runtime.h>

#define F_IN 512
#define HDIM 64
#define NCLS 40
#define NLAYER 4
#define EPS_F 0.2f

__device__ __forceinline__ float wsum(float v) {
#pragma unroll
  for (int off = 32; off > 0; off >>= 1) v += __shfl_xor(v, off, 64);
  return v;
}
__device__ __forceinline__ float wmax(float v) {
#pragma unroll
  for (int off = 32; off > 0; off >>= 1) v = fmaxf(v, __shfl_xor(v, off, 64));
  return v;
}

// ---------------- CSR build ----------------
__global__ __launch_bounds__(256) void k_init_n(int* indeg, int* fill, int nN) {
  int i = blockIdx.x * 256 + threadIdx.x;
  if (i < nN) { indeg[i] = 0; fill[i] = 0; }
}

__global__ __launch_bounds__(256) void k_hist(const int* __restrict__ dst, int* indeg, int nE) {
  int e = blockIdx.x * 256 + threadIdx.x;
  if (e < nE) atomicAdd(&indeg[dst[e]], 1);
}

__global__ __launch_bounds__(256) void k_dinv(const int* __restrict__ indeg, float* dinv, int nN) {
  int i = blockIdx.x * 256 + threadIdx.x;
  if (i < nN) dinv[i] = rsqrtf((float)indeg[i] + 1.0f);  // +1 self-loop
}

// per-512-chunk sums
__global__ __launch_bounds__(256) void k_bsum(const int* __restrict__ indeg, int* bsum, int nN) {
  int i0 = blockIdx.x * 512 + threadIdx.x;
  int v = 0;
  if (i0 < nN) v += indeg[i0];
  if (i0 + 256 < nN) v += indeg[i0 + 256];
#pragma unroll
  for (int off = 32; off > 0; off >>= 1) v += __shfl_xor(v, off, 64);
  __shared__ int s[4];
  if ((threadIdx.x & 63) == 0) s[threadIdx.x >> 6] = v;
  __syncthreads();
  if (threadIdx.x == 0) bsum[blockIdx.x] = s[0] + s[1] + s[2] + s[3];
}

// exclusive scan of <=128 block sums (single block)
__global__ __launch_bounds__(128) void k_bscan(const int* __restrict__ bsum, int* bpre,
                                               int* rowptr, int nblk, int nN, int nE) {
  __shared__ int sb[128];
  int t = threadIdx.x;
  int v = (t < nblk) ? bsum[t] : 0;
  sb[t] = v;
  __syncthreads();
  int acc = v;
  for (int off = 1; off < 128; off <<= 1) {
    int o = (t >= off) ? sb[t - off] : 0;
    __syncthreads();
    acc += o;
    sb[t] = acc;
    __syncthreads();
  }
  if (t < nblk) bpre[t] = acc - v;
  if (t == 0) rowptr[nN] = nE;
}

// per-chunk exclusive scan -> rowptr
__global__ __launch_bounds__(512) void k_rowptr(const int* __restrict__ indeg,
                                                const int* __restrict__ bpre, int* rowptr, int nN) {
  __shared__ int sb[512];
  int t = threadIdx.x;
  int i = blockIdx.x * 512 + t;
  int v = (i < nN) ? indeg[i] : 0;
  sb[t] = v;
  __syncthreads();
  int acc = v;
  for (int off = 1; off < 512; off <<= 1) {
    int o = (t >= off) ? sb[t - off] : 0;
    __syncthreads();
    acc += o;
    sb[t] = acc;
    __syncthreads();
  }
  if (i < nN) rowptr[i] = bpre[blockIdx.x] + acc - v;
}

__global__ __launch_bounds__(256) void k_scatter(const int* __restrict__ src,
                                                 const int* __restrict__ dst,
                                                 const int* __restrict__ rowptr, int* fill,
                                                 int* csrsrc, int* csrdst, int nE) {
  int e = blockIdx.x * 256 + threadIdx.x;
  if (e < nE) {
    int d = dst[e];
    int p = atomicAdd(&fill[d], 1);
    int q = rowptr[d] + p;
    csrsrc[q] = src[e];
    csrdst[q] = d;
  }
}

// ---------------- lin1: h = relu(x @ W1^T + b1), 64x64 output tile ----------------
__global__ __launch_bounds__(256) void k_lin1(const float* __restrict__ x,
                                              const float* __restrict__ W1,
                                              const float* __restrict__ b1,
                                              float* __restrict__ out, int nN) {
  __shared__ float xs[64][33];  // [node][kk]
  __shared__ float ws[32][64];  // [kk][j]
  const int tid = threadIdx.x;
  const int n0 = blockIdx.x * 64;
  const int ng = tid >> 4;         // 0..15
  const int fc = (tid & 15) << 2;  // 0,4,...,60
  const int nr = ng << 2;          // 0,4,...,60
  float acc[4][4] = {{0.f, 0.f, 0.f, 0.f},
                     {0.f, 0.f, 0.f, 0.f},
                     {0.f, 0.f, 0.f, 0.f},
                     {0.f, 0.f, 0.f, 0.f}};
  const int ld_row = tid >> 3;        // 0..31
  const int ld_kkb = (tid & 7) << 2;  // 0,4,...,28

  for (int k0 = 0; k0 < F_IN; k0 += 32) {
#pragma unroll
    for (int r = 0; r < 2; ++r) {
      int nl = ld_row + r * 32;
      int n = n0 + nl;
      float4 v = make_float4(0.f, 0.f, 0.f, 0.f);
      if (n < nN) v = *reinterpret_cast<const float4*>(&x[(size_t)n * F_IN + k0 + ld_kkb]);
      xs[nl][ld_kkb + 0] = v.x;
      xs[nl][ld_kkb + 1] = v.y;
      xs[nl][ld_kkb + 2] = v.z;
      xs[nl][ld_kkb + 3] = v.w;
    }
#pragma unroll
    for (int r = 0; r < 2; ++r) {
      int j = ld_row + r * 32;
      float4 v = *reinterpret_cast<const float4*>(&W1[(size_t)j * F_IN + k0 + ld_kkb]);
      ws[ld_kkb + 0][j] = v.x;
      ws[ld_kkb + 1][j] = v.y;
      ws[ld_kkb + 2][j] = v.z;
      ws[ld_kkb + 3][j] = v.w;
    }
    __syncthreads();
#pragma unroll
    for (int kk = 0; kk < 32; ++kk) {
      float a0 = xs[nr + 0][kk];
      float a1 = xs[nr + 1][kk];
      float a2 = xs[nr + 2][kk];
      float a3 = xs[nr + 3][kk];
      const float4 b = *reinterpret_cast<const float4*>(&ws[kk][fc]);
      acc[0][0] = fmaf(a0, b.x, acc[0][0]); acc[0][1] = fmaf(a0, b.y, acc[0][1]);
      acc[0][2] = fmaf(a0, b.z, acc[0][2]); acc[0][3] = fmaf(a0, b.w, acc[0][3]);
      acc[1][0] = fmaf(a1, b.x, acc[1][0]); acc[1][1] = fmaf(a1, b.y, acc[1][1]);
      acc[1][2] = fmaf(a1, b.z, acc[1][2]); acc[1][3] = fmaf(a1, b.w, acc[1][3]);
      acc[2][0] = fmaf(a2, b.x, acc[2][0]); acc[2][1] = fmaf(a2, b.y, acc[2][1]);
      acc[2][2] = fmaf(a2, b.z, acc[2][2]); acc[2][3] = fmaf(a2, b.w, acc[2][3]);
      acc[3][0] = fmaf(a3, b.x, acc[3][0]); acc[3][1] = fmaf(a3, b.y, acc[3][1]);
      acc[3][2] = fmaf(a3, b.z, acc[3][2]); acc[3][3] = fmaf(a3, b.w, acc[3][3]);
    }
    __syncthreads();
  }
  const float4 bb = *reinterpret_cast<const float4*>(&b1[fc]);
#pragma unroll
  for (int i = 0; i < 4; ++i) {
    int n = n0 + nr + i;
    if (n < nN) {
      float4 o;
      o.x = fmaxf(acc[i][0] + bb.x, 0.f);
      o.y = fmaxf(acc[i][1] + bb.y, 0.f);
      o.z = fmaxf(acc[i][2] + bb.z, 0.f);
      o.w = fmaxf(acc[i][3] + bb.w, 0.f);
      *reinterpret_cast<float4*>(&out[(size_t)n * HDIM + fc]) = o;
    }
  }
}

// ---------------- per-layer scores + self coefficient ----------------
__global__ __launch_bounds__(256) void k_scores(const float* __restrict__ h,
                                                const float* __restrict__ attl,
                                                const float* __restrict__ attr,
                                                const float* __restrict__ dinv,
                                                float* __restrict__ al, float* __restrict__ ar,
                                                float* __restrict__ selfc, int nN) {
  int wid = threadIdx.x >> 6, lane = threadIdx.x & 63;
  int n = blockIdx.x * 4 + wid;
  if (n >= nN) return;
  float v = h[(size_t)n * HDIM + lane];
  float sl = wsum(v * attl[lane]);
  float sr = wsum(v * attr[lane]);
  if (lane == 0) {
    al[n] = sl;
    ar[n] = sr;
    float dv = dinv[n];
    selfc[n] = tanhf(sl + sr) * dv * dv;
  }
}

// ---------------- per-layer edge coefficients: esc[e] = {src, coef} ----------------
__global__ __launch_bounds__(256) void k_coef(const int* __restrict__ csrsrc,
                                              const int* __restrict__ csrdst,
                                              const float* __restrict__ al,
                                              const float* __restrict__ ar,
                                              const float* __restrict__ dinv,
                                              int2* __restrict__ esc, int nE) {
  int e = blockIdx.x * 256 + threadIdx.x;
  if (e < nE) {
    int s = csrsrc[e], d = csrdst[e];
    float c = tanhf(al[s] + ar[d]) * (dinv[s] * dinv[d]);
    esc[e] = make_int2(s, __float_as_int(c));
  }
}

// ---------------- per-layer aggregation: wave per dest, 2 edges in parallel ----------------
__global__ __launch_bounds__(256) void k_aggregate(const float* __restrict__ h,
                                                   const float* __restrict__ raw,
                                                   const int* __restrict__ rowptr,
                                                   const int2* __restrict__ esc,
                                                   const float* __restrict__ selfc,
                                                   float* __restrict__ hout, int nN) {
  int wid = threadIdx.x >> 6, lane = threadIdx.x & 63;
  int d = blockIdx.x * 4 + wid;
  if (d >= nN) return;
  const int half = lane >> 5;       // which edge slot (0/1)
  const int fl = (lane & 31) << 1;  // feature pair 0,2,...,62
  const size_t base = (size_t)d * HDIM + fl;
  float2 acc;
  if (half == 0) {
    float sc = selfc[d];
    float2 hd = *reinterpret_cast<const float2*>(&h[base]);
    float2 rw = *reinterpret_cast<const float2*>(&raw[base]);
    acc.x = fmaf(hd.x, sc, EPS_F * rw.x);
    acc.y = fmaf(hd.y, sc, EPS_F * rw.y);
  } else {
    acc.x = 0.f;
    acc.y = 0.f;
  }
  const int e1 = rowptr[d + 1];
  int e = rowptr[d] + half;
  // 2 edges/wave x 2 unroll = 4 gathers in flight
  for (; e + 2 < e1; e += 4) {
    int2 v0 = esc[e];
    int2 v1 = esc[e + 2];
    const float2 h0 = *reinterpret_cast<const float2*>(&h[(size_t)v0.x * HDIM + fl]);
    const float2 h1 = *reinterpret_cast<const float2*>(&h[(size_t)v1.x * HDIM + fl]);
    const float c0 = __int_as_float(v0.y);
    const float c1 = __int_as_float(v1.y);
    acc.x = fmaf(h0.x, c0, acc.x);
    acc.y = fmaf(h0.y, c0, acc.y);
    acc.x = fmaf(h1.x, c1, acc.x);
    acc.y = fmaf(h1.y, c1, acc.y);
  }
  if (e < e1) {
    int2 v = esc[e];
    const float2 hs = *reinterpret_cast<const float2*>(&h[(size_t)v.x * HDIM + fl]);
    const float c = __int_as_float(v.y);
    acc.x = fmaf(hs.x, c, acc.x);
    acc.y = fmaf(hs.y, c, acc.y);
  }
  // combine the two halves (lane l and l+32 hold the same feature pair)
  acc.x += __shfl_xor(acc.x, 32, 64);
  acc.y += __shfl_xor(acc.y, 32, 64);
  if (half == 0) *reinterpret_cast<float2*>(&hout[base]) = acc;
}

// ---------------- output: logits + log_softmax ----------------
__global__ __launch_bounds__(256) void k_out(const float* __restrict__ h,
                                             const float* __restrict__ W2,
                                             const float* __restrict__ b2,
                                             float* __restrict__ out, int nN) {
  __shared__ float w2t[HDIM][NCLS];  // [j][c]
  for (int i = threadIdx.x; i < HDIM * NCLS; i += 256) {
    int c = i / HDIM, j = i % HDIM;
    w2t[j][c] = W2[i];
  }
  __syncthreads();
  int wid = threadIdx.x >> 6, lane = threadIdx.x & 63;
  int n = blockIdx.x * 4 + wid;
  if (n >= nN) return;
  float hv = h[(size_t)n * HDIM + lane];
  int cidx = (lane < NCLS) ? lane : 0;
  float acc = 0.f;
#pragma unroll
  for (int j = 0; j < HDIM; ++j) {
    float xj = __shfl(hv, j, 64);
    acc = fmaf(xj, w2t[j][cidx], acc);
  }
  float logit = (lane < NCLS) ? (b2[lane] + acc) : -INFINITY;
  float m = wmax(logit);
  float ex = (lane < NCLS) ? expf(logit - m) : 0.f;
  float s = wsum(ex);
  if (lane < NCLS) out[(size_t)n * NCLS + lane] = logit - m - logf(s);
}

extern "C" void kernel_launch(void* const* d_in, const int* in_sizes, int n_in,
                              void* d_out, int out_size, void* d_ws, size_t ws_size,
                              hipStream_t stream) {
  const float* x = (const float*)d_in[0];
  const int* ei = (const int*)d_in[1];
  const float* W1 = (const float*)d_in[2];
  const float* b1 = (const float*)d_in[3];
  const float* W2 = (const float*)d_in[4];
  const float* b2 = (const float*)d_in[5];
  const float* attl = (const float*)d_in[6];
  const float* attr = (const float*)d_in[7];
  float* out = (float*)d_out;

  const int nN = in_sizes[0] / F_IN;
  const int nE = in_sizes[1] / 2;
  const int* src = ei;
  const int* dst = ei + nE;

  char* w = (char*)d_ws;
  size_t off = 0;
  auto alloc = [&](size_t bytes) {
    void* p = (void*)(w + off);
    off = (off + bytes + 255) & ~(size_t)255;
    return p;
  };
  float* raw = (float*)alloc((size_t)nN * HDIM * 4);
  float* hA = (float*)alloc((size_t)nN * HDIM * 4);
  float* hB = (float*)alloc((size_t)nN * HDIM * 4);
  float* al = (float*)alloc((size_t)nN * 4);
  float* ar = (float*)alloc((size_t)nN * 4);
  float* dinv = (float*)alloc((size_t)nN * 4);
  float* selfc = (float*)alloc((size_t)nN * 4);
  int* indeg = (int*)alloc((size_t)nN * 4);
  int* fill = (int*)alloc((size_t)nN * 4);
  int* rowptr = (int*)alloc((size_t)(nN + 1) * 4);
  int* csrsrc = (int*)alloc((size_t)nE * 4);
  int* csrdst = (int*)alloc((size_t)nE * 4);
  int2* esc = (int2*)alloc((size_t)nE * 8);
  int* bsum = (int*)alloc(1024);
  int* bpre = (int*)alloc(1024);

  const int nb_n = (nN + 255) / 256;
  const int nb_e = (nE + 255) / 256;
  const int nblk = (nN + 511) / 512;  // 98 <= 128
  const int nb4 = (nN + 3) / 4;

  k_init_n<<<nb_n, 256, 0, stream>>>(indeg, fill, nN);
  k_hist<<<nb_e, 256, 0, stream>>>(dst, indeg, nE);
  k_dinv<<<nb_n, 256, 0, stream>>>(indeg, dinv, nN);
  k_bsum<<<nblk, 256, 0, stream>>>(indeg, bsum, nN);
  k_bscan<<<1, 128, 0, stream>>>(bsum, bpre, rowptr, nblk, nN, nE);
  k_rowptr<<<nblk, 512, 0, stream>>>(indeg, bpre, rowptr, nN);
  k_scatter<<<nb_e, 256, 0, stream>>>(src, dst, rowptr, fill, csrsrc, csrdst, nE);
  k_lin1<<<(nN + 63) / 64, 256, 0, stream>>>(x, W1, b1, raw, nN);

  const float* hin = raw;
  float* hout = hA;
  for (int l = 0; l < NLAYER; ++l) {
    k_scores<<<nb4, 256, 0, stream>>>(hin, attl + l * HDIM, attr + l * HDIM, dinv, al, ar, selfc, nN);
    k_coef<<<nb_e, 256, 0, stream>>>(csrsrc, csrdst, al, ar, dinv, esc, nE);
    k_aggregate<<<nb4, 256, 0, stream>>>(hin, raw, rowptr, esc, selfc, hout, nN);
    hin = hout;
    hout = (hout == hA) ? hB : hA;
  }
  k_out<<<nb4, 256, 0, stream>>>(hin, W2, b2, out, nN);
}

// Round 3
// 406.176 us; speedup vs baseline: 1.6927x; 1.1833x over previous
//
#include <hip/hip_runtime.h>

#define F_IN 512
#define HDIM 64
#define NCLS 40
#define NLAYER 4
#define EPS_F 0.2f

__device__ __forceinline__ float wsum(float v) {
#pragma unroll
  for (int off = 32; off > 0; off >>= 1) v += __shfl_xor(v, off, 64);
  return v;
}
__device__ __forceinline__ float wmax(float v) {
#pragma unroll
  for (int off = 32; off > 0; off >>= 1) v = fmaxf(v, __shfl_xor(v, off, 64));
  return v;
}

// ---------------- CSR build ----------------
__global__ __launch_bounds__(256) void k_init_n(int* indeg, int* fill, int nN) {
  int i = blockIdx.x * 256 + threadIdx.x;
  if (i < nN) { indeg[i] = 0; fill[i] = 0; }
}

__global__ __launch_bounds__(256) void k_hist(const int* __restrict__ dst, int* indeg, int nE) {
  int e = blockIdx.x * 256 + threadIdx.x;
  if (e < nE) atomicAdd(&indeg[dst[e]], 1);
}

__global__ __launch_bounds__(256) void k_dinv(const int* __restrict__ indeg, float* dinv, int nN) {
  int i = blockIdx.x * 256 + threadIdx.x;
  if (i < nN) dinv[i] = rsqrtf((float)indeg[i] + 1.0f);  // +1 self-loop
}

// per-512-chunk sums
__global__ __launch_bounds__(256) void k_bsum(const int* __restrict__ indeg, int* bsum, int nN) {
  int i0 = blockIdx.x * 512 + threadIdx.x;
  int v = 0;
  if (i0 < nN) v += indeg[i0];
  if (i0 + 256 < nN) v += indeg[i0 + 256];
#pragma unroll
  for (int off = 32; off > 0; off >>= 1) v += __shfl_xor(v, off, 64);
  __shared__ int s[4];
  if ((threadIdx.x & 63) == 0) s[threadIdx.x >> 6] = v;
  __syncthreads();
  if (threadIdx.x == 0) bsum[blockIdx.x] = s[0] + s[1] + s[2] + s[3];
}

// exclusive scan of <=128 block sums (single block)
__global__ __launch_bounds__(128) void k_bscan(const int* __restrict__ bsum, int* bpre,
                                               int* rowptr, int nblk, int nN, int nE) {
  __shared__ int sb[128];
  int t = threadIdx.x;
  int v = (t < nblk) ? bsum[t] : 0;
  sb[t] = v;
  __syncthreads();
  int acc = v;
  for (int off = 1; off < 128; off <<= 1) {
    int o = (t >= off) ? sb[t - off] : 0;
    __syncthreads();
    acc += o;
    sb[t] = acc;
    __syncthreads();
  }
  if (t < nblk) bpre[t] = acc - v;
  if (t == 0) rowptr[nN] = nE;
}

// per-chunk exclusive scan -> rowptr
__global__ __launch_bounds__(512) void k_rowptr(const int* __restrict__ indeg,
                                                const int* __restrict__ bpre, int* rowptr, int nN) {
  __shared__ int sb[512];
  int t = threadIdx.x;
  int i = blockIdx.x * 512 + t;
  int v = (i < nN) ? indeg[i] : 0;
  sb[t] = v;
  __syncthreads();
  int acc = v;
  for (int off = 1; off < 512; off <<= 1) {
    int o = (t >= off) ? sb[t - off] : 0;
    __syncthreads();
    acc += o;
    sb[t] = acc;
    __syncthreads();
  }
  if (i < nN) rowptr[i] = bpre[blockIdx.x] + acc - v;
}

__global__ __launch_bounds__(256) void k_scatter(const int* __restrict__ src,
                                                 const int* __restrict__ dst,
                                                 const int* __restrict__ rowptr, int* fill,
                                                 int* csrsrc, int nE) {
  int e = blockIdx.x * 256 + threadIdx.x;
  if (e < nE) {
    int d = dst[e];
    int p = atomicAdd(&fill[d], 1);
    csrsrc[rowptr[d] + p] = src[e];
  }
}

// ---------------- one-time W1 transpose: W1[64][512] -> w1t[512][64] ----------------
__global__ __launch_bounds__(256) void k_w1t(const float* __restrict__ W1, float* __restrict__ w1t) {
  int idx = blockIdx.x * 256 + threadIdx.x;
  if (idx < HDIM * F_IN) {
    int j = idx >> 9, k = idx & (F_IN - 1);
    w1t[(size_t)k * HDIM + j] = W1[idx];
  }
}

// ---------------- lin1: h = relu(x @ W1^T + b1), 128x64 tile, 8x4 per thread ----------------
#define BN 128
#define BK 32
__global__ __launch_bounds__(256) void k_lin1(const float* __restrict__ x,
                                              const float* __restrict__ w1t,
                                              const float* __restrict__ b1,
                                              float* __restrict__ out, int nN) {
  __shared__ float xs[BK][BN + 4];  // row stride 132 floats = 528 B (16B aligned)
  __shared__ float ws[BK][HDIM];    // [kk][j], float4 rows
  const int t = threadIdx.x;
  const int n0 = blockIdx.x * BN;
  const int fc = (t & 15) << 2;  // 0..60
  const int nr = (t >> 4) << 3;  // 0..120
  float acc[8][4] = {};

  for (int k0 = 0; k0 < F_IN; k0 += BK) {
    // stage x transposed: 128 nodes x 32 k
#pragma unroll
    for (int r = 0; r < 4; ++r) {
      int idx = r * 256 + t;
      int node = idx >> 3;
      int kq = (idx & 7) << 2;
      int n = n0 + node;
      float4 v = make_float4(0.f, 0.f, 0.f, 0.f);
      if (n < nN) v = *reinterpret_cast<const float4*>(&x[(size_t)n * F_IN + k0 + kq]);
      xs[kq + 0][node] = v.x;
      xs[kq + 1][node] = v.y;
      xs[kq + 2][node] = v.z;
      xs[kq + 3][node] = v.w;
    }
    // stage w1t rows (already [k][j]): aligned float4, conflict-free
#pragma unroll
    for (int r = 0; r < 2; ++r) {
      int idx = r * 256 + t;
      int kk = idx >> 4;
      int jq = (idx & 15) << 2;
      *reinterpret_cast<float4*>(&ws[kk][jq]) =
          *reinterpret_cast<const float4*>(&w1t[(size_t)(k0 + kk) * HDIM + jq]);
    }
    __syncthreads();
#pragma unroll
    for (int kk = 0; kk < BK; ++kk) {
      const float4 a0 = *reinterpret_cast<const float4*>(&xs[kk][nr]);
      const float4 a1 = *reinterpret_cast<const float4*>(&xs[kk][nr + 4]);
      const float4 b = *reinterpret_cast<const float4*>(&ws[kk][fc]);
      acc[0][0] = fmaf(a0.x, b.x, acc[0][0]); acc[0][1] = fmaf(a0.x, b.y, acc[0][1]);
      acc[0][2] = fmaf(a0.x, b.z, acc[0][2]); acc[0][3] = fmaf(a0.x, b.w, acc[0][3]);
      acc[1][0] = fmaf(a0.y, b.x, acc[1][0]); acc[1][1] = fmaf(a0.y, b.y, acc[1][1]);
      acc[1][2] = fmaf(a0.y, b.z, acc[1][2]); acc[1][3] = fmaf(a0.y, b.w, acc[1][3]);
      acc[2][0] = fmaf(a0.z, b.x, acc[2][0]); acc[2][1] = fmaf(a0.z, b.y, acc[2][1]);
      acc[2][2] = fmaf(a0.z, b.z, acc[2][2]); acc[2][3] = fmaf(a0.z, b.w, acc[2][3]);
      acc[3][0] = fmaf(a0.w, b.x, acc[3][0]); acc[3][1] = fmaf(a0.w, b.y, acc[3][1]);
      acc[3][2] = fmaf(a0.w, b.z, acc[3][2]); acc[3][3] = fmaf(a0.w, b.w, acc[3][3]);
      acc[4][0] = fmaf(a1.x, b.x, acc[4][0]); acc[4][1] = fmaf(a1.x, b.y, acc[4][1]);
      acc[4][2] = fmaf(a1.x, b.z, acc[4][2]); acc[4][3] = fmaf(a1.x, b.w, acc[4][3]);
      acc[5][0] = fmaf(a1.y, b.x, acc[5][0]); acc[5][1] = fmaf(a1.y, b.y, acc[5][1]);
      acc[5][2] = fmaf(a1.y, b.z, acc[5][2]); acc[5][3] = fmaf(a1.y, b.w, acc[5][3]);
      acc[6][0] = fmaf(a1.z, b.x, acc[6][0]); acc[6][1] = fmaf(a1.z, b.y, acc[6][1]);
      acc[6][2] = fmaf(a1.z, b.z, acc[6][2]); acc[6][3] = fmaf(a1.z, b.w, acc[6][3]);
      acc[7][0] = fmaf(a1.w, b.x, acc[7][0]); acc[7][1] = fmaf(a1.w, b.y, acc[7][1]);
      acc[7][2] = fmaf(a1.w, b.z, acc[7][2]); acc[7][3] = fmaf(a1.w, b.w, acc[7][3]);
    }
    __syncthreads();
  }
  const float4 bb = *reinterpret_cast<const float4*>(&b1[fc]);
#pragma unroll
  for (int i = 0; i < 8; ++i) {
    int n = n0 + nr + i;
    if (n < nN) {
      float4 o;
      o.x = fmaxf(acc[i][0] + bb.x, 0.f);
      o.y = fmaxf(acc[i][1] + bb.y, 0.f);
      o.z = fmaxf(acc[i][2] + bb.z, 0.f);
      o.w = fmaxf(acc[i][3] + bb.w, 0.f);
      *reinterpret_cast<float4*>(&out[(size_t)n * HDIM + fc]) = o;
    }
  }
}

// ---------------- per-layer scores: sp={al,dinv}, ar, selfc ----------------
__global__ __launch_bounds__(256) void k_scores(const float* __restrict__ h,
                                                const float* __restrict__ attl,
                                                const float* __restrict__ attr,
                                                const float* __restrict__ dinv,
                                                float2* __restrict__ sp, float* __restrict__ ar,
                                                float* __restrict__ selfc, int nN) {
  int wid = threadIdx.x >> 6, lane = threadIdx.x & 63;
  int n = blockIdx.x * 4 + wid;
  if (n >= nN) return;
  float v = h[(size_t)n * HDIM + lane];
  float sl = wsum(v * attl[lane]);
  float sr = wsum(v * attr[lane]);
  if (lane == 0) {
    float dv = dinv[n];
    sp[n] = make_float2(sl, dv);
    ar[n] = sr;
    selfc[n] = tanhf(sl + sr) * dv * dv;
  }
}

// ---------------- fused coef+aggregation: wave per dest, 4 edges x 16 lanes ----------------
__global__ __launch_bounds__(256) void k_aggregate(const float* __restrict__ h,
                                                   const float* __restrict__ raw,
                                                   const int* __restrict__ rowptr,
                                                   const int* __restrict__ csrsrc,
                                                   const float2* __restrict__ sp,
                                                   const float* __restrict__ ar,
                                                   const float* __restrict__ selfc,
                                                   float* __restrict__ hout, int nN) {
  int wid = threadIdx.x >> 6, lane = threadIdx.x & 63;
  int d = blockIdx.x * 4 + wid;
  if (d >= nN) return;
  const int grp = lane >> 4;        // edge slot 0..3
  const int fl = (lane & 15) << 2;  // feature 0,4,...,60
  const size_t base = (size_t)d * HDIM + fl;
  const float ar_d = ar[d];
  const float dv_d = sp[d].y;
  float4 acc = make_float4(0.f, 0.f, 0.f, 0.f);
  if (grp == 0) {
    const float sc = selfc[d];
    const float4 hd = *reinterpret_cast<const float4*>(&h[base]);
    const float4 rw = *reinterpret_cast<const float4*>(&raw[base]);
    acc.x = fmaf(hd.x, sc, EPS_F * rw.x);
    acc.y = fmaf(hd.y, sc, EPS_F * rw.y);
    acc.z = fmaf(hd.z, sc, EPS_F * rw.z);
    acc.w = fmaf(hd.w, sc, EPS_F * rw.w);
  }
  const int e1 = rowptr[d + 1];
  int e = rowptr[d] + grp;
  // 4 edge groups x 2 unroll = 8 gather chains in flight per wave
  for (; e + 4 < e1; e += 8) {
    const int s0 = csrsrc[e];
    const int s1 = csrsrc[e + 4];
    const float2 p0 = sp[s0];
    const float2 p1 = sp[s1];
    const float4 h0 = *reinterpret_cast<const float4*>(&h[(size_t)s0 * HDIM + fl]);
    const float4 h1 = *reinterpret_cast<const float4*>(&h[(size_t)s1 * HDIM + fl]);
    const float c0 = tanhf(p0.x + ar_d) * (p0.y * dv_d);
    const float c1 = tanhf(p1.x + ar_d) * (p1.y * dv_d);
    acc.x = fmaf(h0.x, c0, acc.x);
    acc.y = fmaf(h0.y, c0, acc.y);
    acc.z = fmaf(h0.z, c0, acc.z);
    acc.w = fmaf(h0.w, c0, acc.w);
    acc.x = fmaf(h1.x, c1, acc.x);
    acc.y = fmaf(h1.y, c1, acc.y);
    acc.z = fmaf(h1.z, c1, acc.z);
    acc.w = fmaf(h1.w, c1, acc.w);
  }
  if (e < e1) {
    const int s = csrsrc[e];
    const float2 p = sp[s];
    const float4 hs = *reinterpret_cast<const float4*>(&h[(size_t)s * HDIM + fl]);
    const float c = tanhf(p.x + ar_d) * (p.y * dv_d);
    acc.x = fmaf(hs.x, c, acc.x);
    acc.y = fmaf(hs.y, c, acc.y);
    acc.z = fmaf(hs.z, c, acc.z);
    acc.w = fmaf(hs.w, c, acc.w);
  }
  // reduce the 4 edge groups (lanes l, l^16, l^32, l^48 share features)
#pragma unroll
  for (int off = 16; off <= 32; off <<= 1) {
    acc.x += __shfl_xor(acc.x, off, 64);
    acc.y += __shfl_xor(acc.y, off, 64);
    acc.z += __shfl_xor(acc.z, off, 64);
    acc.w += __shfl_xor(acc.w, off, 64);
  }
  if (grp == 0) *reinterpret_cast<float4*>(&hout[base]) = acc;
}

// ---------------- output: logits + log_softmax ----------------
__global__ __launch_bounds__(256) void k_out(const float* __restrict__ h,
                                             const float* __restrict__ W2,
                                             const float* __restrict__ b2,
                                             float* __restrict__ out, int nN) {
  __shared__ float w2t[HDIM][NCLS];  // [j][c]
  for (int i = threadIdx.x; i < HDIM * NCLS; i += 256) {
    int c = i / HDIM, j = i % HDIM;
    w2t[j][c] = W2[i];
  }
  __syncthreads();
  int wid = threadIdx.x >> 6, lane = threadIdx.x & 63;
  int n = blockIdx.x * 4 + wid;
  if (n >= nN) return;
  float hv = h[(size_t)n * HDIM + lane];
  int cidx = (lane < NCLS) ? lane : 0;
  float acc = 0.f;
#pragma unroll
  for (int j = 0; j < HDIM; ++j) {
    float xj = __shfl(hv, j, 64);
    acc = fmaf(xj, w2t[j][cidx], acc);
  }
  float logit = (lane < NCLS) ? (b2[lane] + acc) : -INFINITY;
  float m = wmax(logit);
  float ex = (lane < NCLS) ? expf(logit - m) : 0.f;
  float s = wsum(ex);
  if (lane < NCLS) out[(size_t)n * NCLS + lane] = logit - m - logf(s);
}

extern "C" void kernel_launch(void* const* d_in, const int* in_sizes, int n_in,
                              void* d_out, int out_size, void* d_ws, size_t ws_size,
                              hipStream_t stream) {
  const float* x = (const float*)d_in[0];
  const int* ei = (const int*)d_in[1];
  const float* W1 = (const float*)d_in[2];
  const float* b1 = (const float*)d_in[3];
  const float* W2 = (const float*)d_in[4];
  const float* b2 = (const float*)d_in[5];
  const float* attl = (const float*)d_in[6];
  const float* attr = (const float*)d_in[7];
  float* out = (float*)d_out;

  const int nN = in_sizes[0] / F_IN;
  const int nE = in_sizes[1] / 2;
  const int* src = ei;
  const int* dst = ei + nE;

  char* w = (char*)d_ws;
  size_t off = 0;
  auto alloc = [&](size_t bytes) {
    void* p = (void*)(w + off);
    off = (off + bytes + 255) & ~(size_t)255;
    return p;
  };
  float* raw = (float*)alloc((size_t)nN * HDIM * 4);
  float* hA = (float*)alloc((size_t)nN * HDIM * 4);
  float* hB = (float*)alloc((size_t)nN * HDIM * 4);
  float2* sp = (float2*)alloc((size_t)nN * 8);
  float* ar = (float*)alloc((size_t)nN * 4);
  float* dinv = (float*)alloc((size_t)nN * 4);
  float* selfc = (float*)alloc((size_t)nN * 4);
  float* w1t = (float*)alloc((size_t)F_IN * HDIM * 4);
  int* indeg = (int*)alloc((size_t)nN * 4);
  int* fill = (int*)alloc((size_t)nN * 4);
  int* rowptr = (int*)alloc((size_t)(nN + 1) * 4);
  int* csrsrc = (int*)alloc((size_t)nE * 4);
  int* bsum = (int*)alloc(1024);
  int* bpre = (int*)alloc(1024);

  const int nb_n = (nN + 255) / 256;
  const int nb_e = (nE + 255) / 256;
  const int nblk = (nN + 511) / 512;  // 98 <= 128
  const int nb4 = (nN + 3) / 4;

  k_init_n<<<nb_n, 256, 0, stream>>>(indeg, fill, nN);
  k_hist<<<nb_e, 256, 0, stream>>>(dst, indeg, nE);
  k_dinv<<<nb_n, 256, 0, stream>>>(indeg, dinv, nN);
  k_bsum<<<nblk, 256, 0, stream>>>(indeg, bsum, nN);
  k_bscan<<<1, 128, 0, stream>>>(bsum, bpre, rowptr, nblk, nN, nE);
  k_rowptr<<<nblk, 512, 0, stream>>>(indeg, bpre, rowptr, nN);
  k_scatter<<<nb_e, 256, 0, stream>>>(src, dst, rowptr, fill, csrsrc, nE);
  k_w1t<<<(HDIM * F_IN + 255) / 256, 256, 0, stream>>>(W1, w1t);
  k_lin1<<<(nN + BN - 1) / BN, 256, 0, stream>>>(x, w1t, b1, raw, nN);

  const float* hin = raw;
  float* hout = hA;
  for (int l = 0; l < NLAYER; ++l) {
    k_scores<<<nb4, 256, 0, stream>>>(hin, attl + l * HDIM, attr + l * HDIM, dinv, sp, ar, selfc, nN);
    k_aggregate<<<nb4, 256, 0, stream>>>(hin, raw, rowptr, csrsrc, sp, ar, selfc, hout, nN);
    hin = hout;
    hout = (hout == hA) ? hB : hA;
  }
  k_out<<<nb4, 256, 0, stream>>>(hin, W2, b2, out, nN);
}

// Round 4
// 403.476 us; speedup vs baseline: 1.7040x; 1.0067x over previous
//
#include <hip/hip_runtime.h>

#define F_IN 512
#define HDIM 64
#define NCLS 40
#define NLAYER 4
#define EPS_F 0.2f

__device__ __forceinline__ float wsum(float v) {
#pragma unroll
  for (int off = 32; off > 0; off >>= 1) v += __shfl_xor(v, off, 64);
  return v;
}
__device__ __forceinline__ float wmax(float v) {
#pragma unroll
  for (int off = 32; off > 0; off >>= 1) v = fmaxf(v, __shfl_xor(v, off, 64));
  return v;
}

// ---------------- CSR build ----------------
__global__ __launch_bounds__(256) void k_init_n(int* indeg, int* fill, int nN) {
  int i = blockIdx.x * 256 + threadIdx.x;
  if (i < nN) { indeg[i] = 0; fill[i] = 0; }
}

__global__ __launch_bounds__(256) void k_hist(const int* __restrict__ dst, int* indeg, int nE) {
  int e = blockIdx.x * 256 + threadIdx.x;
  if (e < nE) atomicAdd(&indeg[dst[e]], 1);
}

__global__ __launch_bounds__(256) void k_dinv(const int* __restrict__ indeg, float* dinv, int nN) {
  int i = blockIdx.x * 256 + threadIdx.x;
  if (i < nN) dinv[i] = rsqrtf((float)indeg[i] + 1.0f);  // +1 self-loop
}

// per-512-chunk sums
__global__ __launch_bounds__(256) void k_bsum(const int* __restrict__ indeg, int* bsum, int nN) {
  int i0 = blockIdx.x * 512 + threadIdx.x;
  int v = 0;
  if (i0 < nN) v += indeg[i0];
  if (i0 + 256 < nN) v += indeg[i0 + 256];
#pragma unroll
  for (int off = 32; off > 0; off >>= 1) v += __shfl_xor(v, off, 64);
  __shared__ int s[4];
  if ((threadIdx.x & 63) == 0) s[threadIdx.x >> 6] = v;
  __syncthreads();
  if (threadIdx.x == 0) bsum[blockIdx.x] = s[0] + s[1] + s[2] + s[3];
}

// exclusive scan of <=128 block sums (single block)
__global__ __launch_bounds__(128) void k_bscan(const int* __restrict__ bsum, int* bpre,
                                               int* rowptr, int nblk, int nN, int nE) {
  __shared__ int sb[128];
  int t = threadIdx.x;
  int v = (t < nblk) ? bsum[t] : 0;
  sb[t] = v;
  __syncthreads();
  int acc = v;
  for (int off = 1; off < 128; off <<= 1) {
    int o = (t >= off) ? sb[t - off] : 0;
    __syncthreads();
    acc += o;
    sb[t] = acc;
    __syncthreads();
  }
  if (t < nblk) bpre[t] = acc - v;
  if (t == 0) rowptr[nN] = nE;
}

// per-chunk exclusive scan -> rowptr
__global__ __launch_bounds__(512) void k_rowptr(const int* __restrict__ indeg,
                                                const int* __restrict__ bpre, int* rowptr, int nN) {
  __shared__ int sb[512];
  int t = threadIdx.x;
  int i = blockIdx.x * 512 + t;
  int v = (i < nN) ? indeg[i] : 0;
  sb[t] = v;
  __syncthreads();
  int acc = v;
  for (int off = 1; off < 512; off <<= 1) {
    int o = (t >= off) ? sb[t - off] : 0;
    __syncthreads();
    acc += o;
    sb[t] = acc;
    __syncthreads();
  }
  if (i < nN) rowptr[i] = bpre[blockIdx.x] + acc - v;
}

__global__ __launch_bounds__(256) void k_scatter(const int* __restrict__ src,
                                                 const int* __restrict__ dst,
                                                 const int* __restrict__ rowptr, int* fill,
                                                 int* csrsrc, int nE) {
  int e = blockIdx.x * 256 + threadIdx.x;
  if (e < nE) {
    int d = dst[e];
    int p = atomicAdd(&fill[d], 1);
    csrsrc[rowptr[d] + p] = src[e];
  }
}

// ---------------- one-time W1 transpose: W1[64][512] -> w1t[512][64] ----------------
__global__ __launch_bounds__(256) void k_w1t(const float* __restrict__ W1, float* __restrict__ w1t) {
  int idx = blockIdx.x * 256 + threadIdx.x;
  if (idx < HDIM * F_IN) {
    int j = idx >> 9, k = idx & (F_IN - 1);
    w1t[(size_t)k * HDIM + j] = W1[idx];
  }
}

// ---------------- lin1: h = relu(x @ W1^T + b1) ----------------
// 64-node tile, 256 threads: waves 0-1 do k[0,256), waves 2-3 do k[256,512).
// Each half: 128 threads -> 8 nodes x 4 feats per thread. LDS reduce at end.
#define BN 64
#define BK 32
__global__ __launch_bounds__(256) void k_lin1(const float* __restrict__ x,
                                              const float* __restrict__ w1t,
                                              const float* __restrict__ b1,
                                              float* __restrict__ out, int nN) {
  __shared__ float xs[2][BK][BN + 8];  // stride 72 floats: 16B-aligned rows, <=2-way banks
  __shared__ float ws[2][BK][HDIM];
  const int t = threadIdx.x;
  const int half = t >> 7;   // 0 or 1 (wave-aligned)
  const int th = t & 127;
  const int n0 = blockIdx.x * BN;
  const int fc = (th & 15) << 2;   // 0..60
  const int nr = (th >> 4) << 3;   // 0..56
  const int kbase = half * (F_IN / 2);
  const int snode = th >> 3;       // 0..15
  const int skq = (th & 7) << 2;   // 0..28
  float acc[8][4] = {};

  for (int k0 = 0; k0 < F_IN / 2; k0 += BK) {
    // stage x: 64 nodes x 32 k (transposed)
#pragma unroll
    for (int r = 0; r < 4; ++r) {
      int node = snode + r * 16;
      int n = n0 + node;
      float4 v = make_float4(0.f, 0.f, 0.f, 0.f);
      if (n < nN) v = *reinterpret_cast<const float4*>(&x[(size_t)n * F_IN + kbase + k0 + skq]);
      xs[half][skq + 0][node] = v.x;
      xs[half][skq + 1][node] = v.y;
      xs[half][skq + 2][node] = v.z;
      xs[half][skq + 3][node] = v.w;
    }
    // stage w1t rows [k][j]: aligned float4
#pragma unroll
    for (int r = 0; r < 4; ++r) {
      int idx = r * 128 + th;
      int kk = idx >> 4;           // 0..31
      int jq = (idx & 15) << 2;    // 0..60
      *reinterpret_cast<float4*>(&ws[half][kk][jq]) =
          *reinterpret_cast<const float4*>(&w1t[(size_t)(kbase + k0 + kk) * HDIM + jq]);
    }
    __syncthreads();
#pragma unroll
    for (int kk = 0; kk < BK; ++kk) {
      const float4 a0 = *reinterpret_cast<const float4*>(&xs[half][kk][nr]);
      const float4 a1 = *reinterpret_cast<const float4*>(&xs[half][kk][nr + 4]);
      const float4 b = *reinterpret_cast<const float4*>(&ws[half][kk][fc]);
      acc[0][0] = fmaf(a0.x, b.x, acc[0][0]); acc[0][1] = fmaf(a0.x, b.y, acc[0][1]);
      acc[0][2] = fmaf(a0.x, b.z, acc[0][2]); acc[0][3] = fmaf(a0.x, b.w, acc[0][3]);
      acc[1][0] = fmaf(a0.y, b.x, acc[1][0]); acc[1][1] = fmaf(a0.y, b.y, acc[1][1]);
      acc[1][2] = fmaf(a0.y, b.z, acc[1][2]); acc[1][3] = fmaf(a0.y, b.w, acc[1][3]);
      acc[2][0] = fmaf(a0.z, b.x, acc[2][0]); acc[2][1] = fmaf(a0.z, b.y, acc[2][1]);
      acc[2][2] = fmaf(a0.z, b.z, acc[2][2]); acc[2][3] = fmaf(a0.z, b.w, acc[2][3]);
      acc[3][0] = fmaf(a0.w, b.x, acc[3][0]); acc[3][1] = fmaf(a0.w, b.y, acc[3][1]);
      acc[3][2] = fmaf(a0.w, b.z, acc[3][2]); acc[3][3] = fmaf(a0.w, b.w, acc[3][3]);
      acc[4][0] = fmaf(a1.x, b.x, acc[4][0]); acc[4][1] = fmaf(a1.x, b.y, acc[4][1]);
      acc[4][2] = fmaf(a1.x, b.z, acc[4][2]); acc[4][3] = fmaf(a1.x, b.w, acc[4][3]);
      acc[5][0] = fmaf(a1.y, b.x, acc[5][0]); acc[5][1] = fmaf(a1.y, b.y, acc[5][1]);
      acc[5][2] = fmaf(a1.y, b.z, acc[5][2]); acc[5][3] = fmaf(a1.y, b.w, acc[5][3]);
      acc[6][0] = fmaf(a1.z, b.x, acc[6][0]); acc[6][1] = fmaf(a1.z, b.y, acc[6][1]);
      acc[6][2] = fmaf(a1.z, b.z, acc[6][2]); acc[6][3] = fmaf(a1.z, b.w, acc[6][3]);
      acc[7][0] = fmaf(a1.w, b.x, acc[7][0]); acc[7][1] = fmaf(a1.w, b.y, acc[7][1]);
      acc[7][2] = fmaf(a1.w, b.z, acc[7][2]); acc[7][3] = fmaf(a1.w, b.w, acc[7][3]);
    }
    __syncthreads();
  }
  // cross-half reduce through LDS (reuse ws: 1024 float4 = 16 KB)
  float4* red4 = reinterpret_cast<float4*>(&ws[0][0][0]);
  if (half == 1) {
#pragma unroll
    for (int i = 0; i < 8; ++i)
      red4[i * 128 + th] = make_float4(acc[i][0], acc[i][1], acc[i][2], acc[i][3]);
  }
  __syncthreads();
  if (half == 0) {
    const float4 bb = *reinterpret_cast<const float4*>(&b1[fc]);
#pragma unroll
    for (int i = 0; i < 8; ++i) {
      int n = n0 + nr + i;
      if (n < nN) {
        float4 r = red4[i * 128 + th];
        float4 o;
        o.x = fmaxf(acc[i][0] + r.x + bb.x, 0.f);
        o.y = fmaxf(acc[i][1] + r.y + bb.y, 0.f);
        o.z = fmaxf(acc[i][2] + r.z + bb.z, 0.f);
        o.w = fmaxf(acc[i][3] + r.w + bb.w, 0.f);
        *reinterpret_cast<float4*>(&out[(size_t)n * HDIM + fc]) = o;
      }
    }
  }
}

// ---------------- layer-0 scores: sp[n] = {al, dinv, ar, selfc} ----------------
__global__ __launch_bounds__(256) void k_scores(const float* __restrict__ h,
                                                const float* __restrict__ attl,
                                                const float* __restrict__ attr,
                                                const float* __restrict__ dinv,
                                                float4* __restrict__ sp, int nN) {
  int wid = threadIdx.x >> 6, lane = threadIdx.x & 63;
  int n = blockIdx.x * 4 + wid;
  if (n >= nN) return;
  float v = h[(size_t)n * HDIM + lane];
  float sl = wsum(v * attl[lane]);
  float sr = wsum(v * attr[lane]);
  if (lane == 0) {
    float dv = dinv[n];
    sp[n] = make_float4(sl, dv, sr, tanhf(sl + sr) * dv * dv);
  }
}

// ---------------- fused aggregation (+ optional next-layer scores) ----------------
// wave per dest node; 4 edge-groups x 16 lanes x float4 feats; unroll 4 -> 16 edges in flight
template <bool WNEXT>
__global__ __launch_bounds__(256) void k_aggregate(const float* __restrict__ h,
                                                   const float* __restrict__ raw,
                                                   const int* __restrict__ rowptr,
                                                   const int* __restrict__ csrsrc,
                                                   const float4* __restrict__ sp,
                                                   const float* __restrict__ attl_n,
                                                   const float* __restrict__ attr_n,
                                                   float4* __restrict__ sp_n,
                                                   float* __restrict__ hout, int nN) {
  int wid = threadIdx.x >> 6, lane = threadIdx.x & 63;
  int d = blockIdx.x * 4 + wid;
  if (d >= nN) return;
  const int grp = lane >> 4;        // edge slot 0..3
  const int fl = (lane & 15) << 2;  // feature 0,4,...,60
  const size_t base = (size_t)d * HDIM + fl;
  const float4 pd = sp[d];  // {al_d, dinv_d, ar_d, selfc_d}
  const float ar_d = pd.z;
  const float dv_d = pd.y;
  float4 acc = make_float4(0.f, 0.f, 0.f, 0.f);
  if (grp == 0) {
    const float sc = pd.w;
    const float4 hd = *reinterpret_cast<const float4*>(&h[base]);
    const float4 rw = *reinterpret_cast<const float4*>(&raw[base]);
    acc.x = fmaf(hd.x, sc, EPS_F * rw.x);
    acc.y = fmaf(hd.y, sc, EPS_F * rw.y);
    acc.z = fmaf(hd.z, sc, EPS_F * rw.z);
    acc.w = fmaf(hd.w, sc, EPS_F * rw.w);
  }
  const int e1 = rowptr[d + 1];
  int e = rowptr[d] + grp;
  // 4 groups x 4 unroll = 16 edges in flight per wave
  for (; e + 12 < e1; e += 16) {
    const int s0 = csrsrc[e];
    const int s1 = csrsrc[e + 4];
    const int s2 = csrsrc[e + 8];
    const int s3 = csrsrc[e + 12];
    const float4 p0 = sp[s0];
    const float4 p1 = sp[s1];
    const float4 p2 = sp[s2];
    const float4 p3 = sp[s3];
    const float4 h0 = *reinterpret_cast<const float4*>(&h[(size_t)s0 * HDIM + fl]);
    const float4 h1 = *reinterpret_cast<const float4*>(&h[(size_t)s1 * HDIM + fl]);
    const float4 h2 = *reinterpret_cast<const float4*>(&h[(size_t)s2 * HDIM + fl]);
    const float4 h3 = *reinterpret_cast<const float4*>(&h[(size_t)s3 * HDIM + fl]);
    const float c0 = tanhf(p0.x + ar_d) * (p0.y * dv_d);
    const float c1 = tanhf(p1.x + ar_d) * (p1.y * dv_d);
    const float c2 = tanhf(p2.x + ar_d) * (p2.y * dv_d);
    const float c3 = tanhf(p3.x + ar_d) * (p3.y * dv_d);
    acc.x = fmaf(h0.x, c0, acc.x); acc.y = fmaf(h0.y, c0, acc.y);
    acc.z = fmaf(h0.z, c0, acc.z); acc.w = fmaf(h0.w, c0, acc.w);
    acc.x = fmaf(h1.x, c1, acc.x); acc.y = fmaf(h1.y, c1, acc.y);
    acc.z = fmaf(h1.z, c1, acc.z); acc.w = fmaf(h1.w, c1, acc.w);
    acc.x = fmaf(h2.x, c2, acc.x); acc.y = fmaf(h2.y, c2, acc.y);
    acc.z = fmaf(h2.z, c2, acc.z); acc.w = fmaf(h2.w, c2, acc.w);
    acc.x = fmaf(h3.x, c3, acc.x); acc.y = fmaf(h3.y, c3, acc.y);
    acc.z = fmaf(h3.z, c3, acc.z); acc.w = fmaf(h3.w, c3, acc.w);
  }
  for (; e < e1; e += 4) {
    const int s = csrsrc[e];
    const float4 p = sp[s];
    const float4 hs = *reinterpret_cast<const float4*>(&h[(size_t)s * HDIM + fl]);
    const float c = tanhf(p.x + ar_d) * (p.y * dv_d);
    acc.x = fmaf(hs.x, c, acc.x);
    acc.y = fmaf(hs.y, c, acc.y);
    acc.z = fmaf(hs.z, c, acc.z);
    acc.w = fmaf(hs.w, c, acc.w);
  }
  // reduce the 4 edge groups: after this ALL lanes hold the full row slice
#pragma unroll
  for (int off = 16; off <= 32; off <<= 1) {
    acc.x += __shfl_xor(acc.x, off, 64);
    acc.y += __shfl_xor(acc.y, off, 64);
    acc.z += __shfl_xor(acc.z, off, 64);
    acc.w += __shfl_xor(acc.w, off, 64);
  }
  if (grp == 0) *reinterpret_cast<float4*>(&hout[base]) = acc;
  if (WNEXT) {
    // next-layer scores from the row we just produced
    const float4 atl = *reinterpret_cast<const float4*>(&attl_n[fl]);
    const float4 atr = *reinterpret_cast<const float4*>(&attr_n[fl]);
    float psl = acc.x * atl.x + acc.y * atl.y + acc.z * atl.z + acc.w * atl.w;
    float psr = acc.x * atr.x + acc.y * atr.y + acc.z * atr.z + acc.w * atr.w;
#pragma unroll
    for (int off = 1; off <= 8; off <<= 1) {
      psl += __shfl_xor(psl, off, 64);
      psr += __shfl_xor(psr, off, 64);
    }
    if (lane == 0)
      sp_n[d] = make_float4(psl, dv_d, psr, tanhf(psl + psr) * dv_d * dv_d);
  }
}

// ---------------- output: logits + log_softmax ----------------
__global__ __launch_bounds__(256) void k_out(const float* __restrict__ h,
                                             const float* __restrict__ W2,
                                             const float* __restrict__ b2,
                                             float* __restrict__ out, int nN) {
  __shared__ float w2t[HDIM][NCLS];  // [j][c]
  for (int i = threadIdx.x; i < HDIM * NCLS; i += 256) {
    int c = i / HDIM, j = i % HDIM;
    w2t[j][c] = W2[i];
  }
  __syncthreads();
  int wid = threadIdx.x >> 6, lane = threadIdx.x & 63;
  int n = blockIdx.x * 4 + wid;
  if (n >= nN) return;
  float hv = h[(size_t)n * HDIM + lane];
  int cidx = (lane < NCLS) ? lane : 0;
  float acc = 0.f;
#pragma unroll
  for (int j = 0; j < HDIM; ++j) {
    float xj = __shfl(hv, j, 64);
    acc = fmaf(xj, w2t[j][cidx], acc);
  }
  float logit = (lane < NCLS) ? (b2[lane] + acc) : -INFINITY;
  float m = wmax(logit);
  float ex = (lane < NCLS) ? expf(logit - m) : 0.f;
  float s = wsum(ex);
  if (lane < NCLS) out[(size_t)n * NCLS + lane] = logit - m - logf(s);
}

extern "C" void kernel_launch(void* const* d_in, const int* in_sizes, int n_in,
                              void* d_out, int out_size, void* d_ws, size_t ws_size,
                              hipStream_t stream) {
  const float* x = (const float*)d_in[0];
  const int* ei = (const int*)d_in[1];
  const float* W1 = (const float*)d_in[2];
  const float* b1 = (const float*)d_in[3];
  const float* W2 = (const float*)d_in[4];
  const float* b2 = (const float*)d_in[5];
  const float* attl = (const float*)d_in[6];
  const float* attr = (const float*)d_in[7];
  float* out = (float*)d_out;

  const int nN = in_sizes[0] / F_IN;
  const int nE = in_sizes[1] / 2;
  const int* src = ei;
  const int* dst = ei + nE;

  char* w = (char*)d_ws;
  size_t off = 0;
  auto alloc = [&](size_t bytes) {
    void* p = (void*)(w + off);
    off = (off + bytes + 255) & ~(size_t)255;
    return p;
  };
  float* raw = (float*)alloc((size_t)nN * HDIM * 4);
  float* hA = (float*)alloc((size_t)nN * HDIM * 4);
  float* hB = (float*)alloc((size_t)nN * HDIM * 4);
  float4* sp0 = (float4*)alloc((size_t)nN * 16);
  float4* sp1 = (float4*)alloc((size_t)nN * 16);
  float* dinv = (float*)alloc((size_t)nN * 4);
  float* w1t = (float*)alloc((size_t)F_IN * HDIM * 4);
  int* indeg = (int*)alloc((size_t)nN * 4);
  int* fill = (int*)alloc((size_t)nN * 4);
  int* rowptr = (int*)alloc((size_t)(nN + 1) * 4);
  int* csrsrc = (int*)alloc((size_t)nE * 4);
  int* bsum = (int*)alloc(1024);
  int* bpre = (int*)alloc(1024);

  const int nb_n = (nN + 255) / 256;
  const int nb_e = (nE + 255) / 256;
  const int nblk = (nN + 511) / 512;  // 98 <= 128
  const int nb4 = (nN + 3) / 4;

  k_init_n<<<nb_n, 256, 0, stream>>>(indeg, fill, nN);
  k_hist<<<nb_e, 256, 0, stream>>>(dst, indeg, nE);
  k_dinv<<<nb_n, 256, 0, stream>>>(indeg, dinv, nN);
  k_bsum<<<nblk, 256, 0, stream>>>(indeg, bsum, nN);
  k_bscan<<<1, 128, 0, stream>>>(bsum, bpre, rowptr, nblk, nN, nE);
  k_rowptr<<<nblk, 512, 0, stream>>>(indeg, bpre, rowptr, nN);
  k_scatter<<<nb_e, 256, 0, stream>>>(src, dst, rowptr, fill, csrsrc, nE);
  k_w1t<<<(HDIM * F_IN + 255) / 256, 256, 0, stream>>>(W1, w1t);
  k_lin1<<<(nN + BN - 1) / BN, 256, 0, stream>>>(x, w1t, b1, raw, nN);

  k_scores<<<nb4, 256, 0, stream>>>(raw, attl, attr, dinv, sp0, nN);

  const float* hin = raw;
  float* hout = hA;
  float4* spc = sp0;
  float4* spn = sp1;
  for (int l = 0; l < NLAYER; ++l) {
    if (l < NLAYER - 1) {
      k_aggregate<true><<<nb4, 256, 0, stream>>>(hin, raw, rowptr, csrsrc, spc,
                                                 attl + (l + 1) * HDIM, attr + (l + 1) * HDIM,
                                                 spn, hout, nN);
    } else {
      k_aggregate<false><<<nb4, 256, 0, stream>>>(hin, raw, rowptr, csrsrc, spc,
                                                  nullptr, nullptr, nullptr, hout, nN);
    }
    hin = hout;
    hout = (hout == hA) ? hB : hA;
    float4* tmp = spc; spc = spn; spn = tmp;
  }
  k_out<<<nb4, 256, 0, stream>>>(hin, W2, b2, out, nN);
}

// Round 5
// 354.269 us; speedup vs baseline: 1.9407x; 1.1389x over previous
//
#include <hip/hip_runtime.h>

#define F_IN 512
#define HDIM 64
#define NCLS 40
#define NLAYER 4
#define EPS_F 0.2f

typedef __attribute__((ext_vector_type(8))) short short8;
typedef __attribute__((ext_vector_type(4))) float f32x4;
typedef __attribute__((ext_vector_type(8))) unsigned short ushort8;

__device__ __forceinline__ unsigned short f2bf(float f) {
  unsigned u = __float_as_uint(f);
  u += 0x7FFFu + ((u >> 16) & 1u);  // RNE
  return (unsigned short)(u >> 16);
}
__device__ __forceinline__ float bf2f(unsigned short s) {
  return __uint_as_float(((unsigned)s) << 16);
}

__device__ __forceinline__ float wsum(float v) {
#pragma unroll
  for (int off = 32; off > 0; off >>= 1) v += __shfl_xor(v, off, 64);
  return v;
}
__device__ __forceinline__ float wmax(float v) {
#pragma unroll
  for (int off = 32; off > 0; off >>= 1) v = fmaxf(v, __shfl_xor(v, off, 64));
  return v;
}

// ---------------- CSR build ----------------
__global__ __launch_bounds__(256) void k_init_n(int* indeg, int* fill, int nN) {
  int i = blockIdx.x * 256 + threadIdx.x;
  if (i < nN) { indeg[i] = 0; fill[i] = 0; }
}

__global__ __launch_bounds__(256) void k_hist(const int* __restrict__ dst, int* indeg, int nE) {
  int e = blockIdx.x * 256 + threadIdx.x;
  if (e < nE) atomicAdd(&indeg[dst[e]], 1);
}

__global__ __launch_bounds__(256) void k_dinv(const int* __restrict__ indeg, float* dinv, int nN) {
  int i = blockIdx.x * 256 + threadIdx.x;
  if (i < nN) dinv[i] = rsqrtf((float)indeg[i] + 1.0f);  // +1 self-loop
}

__global__ __launch_bounds__(256) void k_bsum(const int* __restrict__ indeg, int* bsum, int nN) {
  int i0 = blockIdx.x * 512 + threadIdx.x;
  int v = 0;
  if (i0 < nN) v += indeg[i0];
  if (i0 + 256 < nN) v += indeg[i0 + 256];
#pragma unroll
  for (int off = 32; off > 0; off >>= 1) v += __shfl_xor(v, off, 64);
  __shared__ int s[4];
  if ((threadIdx.x & 63) == 0) s[threadIdx.x >> 6] = v;
  __syncthreads();
  if (threadIdx.x == 0) bsum[blockIdx.x] = s[0] + s[1] + s[2] + s[3];
}

__global__ __launch_bounds__(128) void k_bscan(const int* __restrict__ bsum, int* bpre,
                                               int* rowptr, int nblk, int nN, int nE) {
  __shared__ int sb[128];
  int t = threadIdx.x;
  int v = (t < nblk) ? bsum[t] : 0;
  sb[t] = v;
  __syncthreads();
  int acc = v;
  for (int off = 1; off < 128; off <<= 1) {
    int o = (t >= off) ? sb[t - off] : 0;
    __syncthreads();
    acc += o;
    sb[t] = acc;
    __syncthreads();
  }
  if (t < nblk) bpre[t] = acc - v;
  if (t == 0) rowptr[nN] = nE;
}

__global__ __launch_bounds__(512) void k_rowptr(const int* __restrict__ indeg,
                                                const int* __restrict__ bpre, int* rowptr, int nN) {
  __shared__ int sb[512];
  int t = threadIdx.x;
  int i = blockIdx.x * 512 + t;
  int v = (i < nN) ? indeg[i] : 0;
  sb[t] = v;
  __syncthreads();
  int acc = v;
  for (int off = 1; off < 512; off <<= 1) {
    int o = (t >= off) ? sb[t - off] : 0;
    __syncthreads();
    acc += o;
    sb[t] = acc;
    __syncthreads();
  }
  if (i < nN) rowptr[i] = bpre[blockIdx.x] + acc - v;
}

__global__ __launch_bounds__(256) void k_scatter(const int* __restrict__ src,
                                                 const int* __restrict__ dst,
                                                 const int* __restrict__ rowptr, int* fill,
                                                 int* csrsrc, int* csrdst, int nE) {
  int e = blockIdx.x * 256 + threadIdx.x;
  if (e < nE) {
    int d = dst[e];
    int p = atomicAdd(&fill[d], 1);
    int q = rowptr[d] + p;
    csrsrc[q] = src[e];
    csrdst[q] = d;
  }
}

// ---------------- lin1: raw = relu(x @ W1^T + b1) via bf16 MFMA ----------------
// Block: 256 thr = 4 waves, tile 64 nodes x 64 feats, K chunks of 64.
// LDS: xs[64 rows][64 k] bf16 + ws[64 feats][64 k] bf16, 16B slots XOR-swizzled by row.
__global__ __launch_bounds__(256) void k_lin1(const float* __restrict__ x,
                                              const float* __restrict__ W1,
                                              const float* __restrict__ b1,
                                              float* __restrict__ raw, int nN) {
  __shared__ unsigned short xs[64 * 64];
  __shared__ unsigned short ws[64 * 64];
  const int t = threadIdx.x;
  const int wv = t >> 6;
  const int l = t & 63;
  const int n0 = blockIdx.x * 64;
  // staging: thread t loads row srow, float4s [sk4, sk4+4) of each 16-float4 chunk row
  const int srow = t >> 2;
  const int sk4 = (t & 3) * 4;
  const bool xvalid = (n0 + srow) < nN;
  const float4* x4 = reinterpret_cast<const float4*>(x);
  const float4* w4 = reinterpret_cast<const float4*>(W1);
  short8* xs8 = reinterpret_cast<short8*>(xs);
  short8* ws8 = reinterpret_cast<short8*>(ws);
  const int wslot0 = srow * 8 + (((t & 3) * 2 + 0) ^ (srow & 7));
  const int wslot1 = srow * 8 + (((t & 3) * 2 + 1) ^ (srow & 7));
  // fragment indices (per lane)
  const int arow = l & 15;
  const int kgrp = l >> 4;
  f32x4 acc[4] = {{0.f, 0.f, 0.f, 0.f},
                  {0.f, 0.f, 0.f, 0.f},
                  {0.f, 0.f, 0.f, 0.f},
                  {0.f, 0.f, 0.f, 0.f}};
  float4 xa[4], wa[4];
  {
    const size_t xb = (size_t)(n0 + srow) * (F_IN / 4) + sk4;
    const size_t wb = (size_t)srow * (F_IN / 4) + sk4;
#pragma unroll
    for (int r = 0; r < 4; ++r) {
      xa[r] = xvalid ? x4[xb + r] : make_float4(0.f, 0.f, 0.f, 0.f);
      wa[r] = w4[wb + r];
    }
  }
  for (int c = 0; c < 8; ++c) {
    // pack regs -> bf16, write LDS
    short8 p0, p1, q0, q1;
    p0[0] = (short)f2bf(xa[0].x); p0[1] = (short)f2bf(xa[0].y);
    p0[2] = (short)f2bf(xa[0].z); p0[3] = (short)f2bf(xa[0].w);
    p0[4] = (short)f2bf(xa[1].x); p0[5] = (short)f2bf(xa[1].y);
    p0[6] = (short)f2bf(xa[1].z); p0[7] = (short)f2bf(xa[1].w);
    p1[0] = (short)f2bf(xa[2].x); p1[1] = (short)f2bf(xa[2].y);
    p1[2] = (short)f2bf(xa[2].z); p1[3] = (short)f2bf(xa[2].w);
    p1[4] = (short)f2bf(xa[3].x); p1[5] = (short)f2bf(xa[3].y);
    p1[6] = (short)f2bf(xa[3].z); p1[7] = (short)f2bf(xa[3].w);
    q0[0] = (short)f2bf(wa[0].x); q0[1] = (short)f2bf(wa[0].y);
    q0[2] = (short)f2bf(wa[0].z); q0[3] = (short)f2bf(wa[0].w);
    q0[4] = (short)f2bf(wa[1].x); q0[5] = (short)f2bf(wa[1].y);
    q0[6] = (short)f2bf(wa[1].z); q0[7] = (short)f2bf(wa[1].w);
    q1[0] = (short)f2bf(wa[2].x); q1[1] = (short)f2bf(wa[2].y);
    q1[2] = (short)f2bf(wa[2].z); q1[3] = (short)f2bf(wa[2].w);
    q1[4] = (short)f2bf(wa[3].x); q1[5] = (short)f2bf(wa[3].y);
    q1[6] = (short)f2bf(wa[3].z); q1[7] = (short)f2bf(wa[3].w);
    xs8[wslot0] = p0;
    xs8[wslot1] = p1;
    ws8[wslot0] = q0;
    ws8[wslot1] = q1;
    __syncthreads();
    if (c < 7) {  // prefetch next chunk under compute
      const size_t xb = (size_t)(n0 + srow) * (F_IN / 4) + (c + 1) * 16 + sk4;
      const size_t wb = (size_t)srow * (F_IN / 4) + (c + 1) * 16 + sk4;
#pragma unroll
      for (int r = 0; r < 4; ++r) {
        xa[r] = xvalid ? x4[xb + r] : make_float4(0.f, 0.f, 0.f, 0.f);
        wa[r] = w4[wb + r];
      }
    }
#pragma unroll
    for (int c2 = 0; c2 < 2; ++c2) {
      const short8 a = xs8[(wv * 16 + arow) * 8 + ((c2 * 4 + kgrp) ^ (arow & 7))];
#pragma unroll
      for (int fs = 0; fs < 4; ++fs) {
        const short8 b = ws8[(fs * 16 + arow) * 8 + ((c2 * 4 + kgrp) ^ (arow & 7))];
        acc[fs] = __builtin_amdgcn_mfma_f32_16x16x32_bf16(a, b, acc[fs], 0, 0, 0);
      }
    }
    __syncthreads();
  }
  // epilogue: D layout col = lane&15, row = (lane>>4)*4 + reg
#pragma unroll
  for (int fs = 0; fs < 4; ++fs) {
    const int feat = fs * 16 + arow;
    const float bias = b1[feat];
#pragma unroll
    for (int j = 0; j < 4; ++j) {
      const int node = n0 + wv * 16 + kgrp * 4 + j;
      if (node < nN) raw[(size_t)node * HDIM + feat] = fmaxf(acc[fs][j] + bias, 0.f);
    }
  }
}

// ---------------- layer-0 scores + bf16 copy of raw ----------------
__global__ __launch_bounds__(256) void k_scores(const float* __restrict__ raw,
                                                const float* __restrict__ attl,
                                                const float* __restrict__ attr,
                                                const float* __restrict__ dinv,
                                                float2* __restrict__ P, float2* __restrict__ Q,
                                                float* __restrict__ selfc,
                                                unsigned short* __restrict__ h0, int nN) {
  int wid = threadIdx.x >> 6, lane = threadIdx.x & 63;
  int n = blockIdx.x * 4 + wid;
  if (n >= nN) return;
  float v = raw[(size_t)n * HDIM + lane];
  h0[(size_t)n * HDIM + lane] = f2bf(v);
  float sl = wsum(v * attl[lane]);
  float sr = wsum(v * attr[lane]);
  if (lane == 0) {
    float dv = dinv[n];
    P[n] = make_float2(sl, dv);
    Q[n] = make_float2(sr, dv);
    selfc[n] = tanhf(sl + sr) * dv * dv;
  }
}

// ---------------- per-layer edge coefficients ----------------
__global__ __launch_bounds__(256) void k_coef(const int* __restrict__ csrsrc,
                                              const int* __restrict__ csrdst,
                                              const float2* __restrict__ P,
                                              const float2* __restrict__ Q,
                                              int2* __restrict__ esc, int nE) {
  int e = blockIdx.x * 256 + threadIdx.x;
  if (e < nE) {
    int s = csrsrc[e], d = csrdst[e];
    float2 p = P[s], q = Q[d];
    float c = tanhf(p.x + q.x) * (p.y * q.y);
    esc[e] = make_int2(s, __float_as_int(c));
  }
}

// ---------------- aggregation: wave/dest, 8 edge-groups x 8 lanes, bf16 gathers ----------------
template <bool WNEXT>
__global__ __launch_bounds__(256) void k_agg(const unsigned short* __restrict__ h,
                                             const float* __restrict__ raw,
                                             const int* __restrict__ rowptr,
                                             const int2* __restrict__ esc,
                                             const float* __restrict__ dinv,
                                             float* __restrict__ selfc,
                                             const float* __restrict__ attl_n,
                                             const float* __restrict__ attr_n,
                                             float2* __restrict__ P, float2* __restrict__ Q,
                                             unsigned short* __restrict__ hout, int nN) {
  const int wid = threadIdx.x >> 6, lane = threadIdx.x & 63;
  const int d = blockIdx.x * 4 + wid;
  if (d >= nN) return;
  const int grp = lane >> 3;
  const int fo = (lane & 7) * 8;
  const size_t base = (size_t)d * HDIM + fo;
  float acc[8] = {};
  if (grp == 0) {
    const float sc = selfc[d];
    const ushort8 hd = *reinterpret_cast<const ushort8*>(&h[base]);
    const float4 r0 = *reinterpret_cast<const float4*>(&raw[base]);
    const float4 r1 = *reinterpret_cast<const float4*>(&raw[base + 4]);
    acc[0] = fmaf(bf2f(hd[0]), sc, EPS_F * r0.x);
    acc[1] = fmaf(bf2f(hd[1]), sc, EPS_F * r0.y);
    acc[2] = fmaf(bf2f(hd[2]), sc, EPS_F * r0.z);
    acc[3] = fmaf(bf2f(hd[3]), sc, EPS_F * r0.w);
    acc[4] = fmaf(bf2f(hd[4]), sc, EPS_F * r1.x);
    acc[5] = fmaf(bf2f(hd[5]), sc, EPS_F * r1.y);
    acc[6] = fmaf(bf2f(hd[6]), sc, EPS_F * r1.z);
    acc[7] = fmaf(bf2f(hd[7]), sc, EPS_F * r1.w);
  }
  const int e1 = rowptr[d + 1];
  int e = rowptr[d] + grp;
  for (; e + 8 < e1; e += 16) {
    const int2 v0 = esc[e];
    const int2 v1 = esc[e + 8];
    const ushort8 h0v = *reinterpret_cast<const ushort8*>(&h[(size_t)v0.x * HDIM + fo]);
    const ushort8 h1v = *reinterpret_cast<const ushort8*>(&h[(size_t)v1.x * HDIM + fo]);
    const float c0 = __int_as_float(v0.y);
    const float c1 = __int_as_float(v1.y);
#pragma unroll
    for (int j = 0; j < 8; ++j) acc[j] = fmaf(bf2f(h0v[j]), c0, acc[j]);
#pragma unroll
    for (int j = 0; j < 8; ++j) acc[j] = fmaf(bf2f(h1v[j]), c1, acc[j]);
  }
  for (; e < e1; e += 8) {
    const int2 v = esc[e];
    const ushort8 hv = *reinterpret_cast<const ushort8*>(&h[(size_t)v.x * HDIM + fo]);
    const float c = __int_as_float(v.y);
#pragma unroll
    for (int j = 0; j < 8; ++j) acc[j] = fmaf(bf2f(hv[j]), c, acc[j]);
  }
  // reduce across the 8 edge-groups (lanes sharing lane&7 hold same feats)
#pragma unroll
  for (int off = 8; off <= 32; off <<= 1) {
#pragma unroll
    for (int j = 0; j < 8; ++j) acc[j] += __shfl_xor(acc[j], off, 64);
  }
  if (grp == 0) {
    ushort8 o;
#pragma unroll
    for (int j = 0; j < 8; ++j) o[j] = f2bf(acc[j]);
    *reinterpret_cast<ushort8*>(&hout[base]) = o;
  }
  if (WNEXT) {
    const float4 al0 = *reinterpret_cast<const float4*>(&attl_n[fo]);
    const float4 al1 = *reinterpret_cast<const float4*>(&attl_n[fo + 4]);
    const float4 ar0 = *reinterpret_cast<const float4*>(&attr_n[fo]);
    const float4 ar1 = *reinterpret_cast<const float4*>(&attr_n[fo + 4]);
    float psl = acc[0] * al0.x + acc[1] * al0.y + acc[2] * al0.z + acc[3] * al0.w +
                acc[4] * al1.x + acc[5] * al1.y + acc[6] * al1.z + acc[7] * al1.w;
    float psr = acc[0] * ar0.x + acc[1] * ar0.y + acc[2] * ar0.z + acc[3] * ar0.w +
                acc[4] * ar1.x + acc[5] * ar1.y + acc[6] * ar1.z + acc[7] * ar1.w;
#pragma unroll
    for (int off = 1; off <= 4; off <<= 1) {
      psl += __shfl_xor(psl, off, 64);
      psr += __shfl_xor(psr, off, 64);
    }
    if (lane == 0) {
      const float dv = dinv[d];
      P[d] = make_float2(psl, dv);
      Q[d] = make_float2(psr, dv);
      selfc[d] = tanhf(psl + psr) * dv * dv;
    }
  }
}

// ---------------- output: logits + log_softmax (bf16 h) ----------------
__global__ __launch_bounds__(256) void k_out(const unsigned short* __restrict__ h,
                                             const float* __restrict__ W2,
                                             const float* __restrict__ b2,
                                             float* __restrict__ out, int nN) {
  __shared__ float w2t[HDIM][NCLS];  // [j][c]
  for (int i = threadIdx.x; i < HDIM * NCLS; i += 256) {
    int c = i / HDIM, j = i % HDIM;
    w2t[j][c] = W2[i];
  }
  __syncthreads();
  int wid = threadIdx.x >> 6, lane = threadIdx.x & 63;
  int n = blockIdx.x * 4 + wid;
  if (n >= nN) return;
  float hv = bf2f(h[(size_t)n * HDIM + lane]);
  int cidx = (lane < NCLS) ? lane : 0;
  float acc = 0.f;
#pragma unroll
  for (int j = 0; j < HDIM; ++j) {
    float xj = __shfl(hv, j, 64);
    acc = fmaf(xj, w2t[j][cidx], acc);
  }
  float logit = (lane < NCLS) ? (b2[lane] + acc) : -INFINITY;
  float m = wmax(logit);
  float ex = (lane < NCLS) ? expf(logit - m) : 0.f;
  float s = wsum(ex);
  if (lane < NCLS) out[(size_t)n * NCLS + lane] = logit - m - logf(s);
}

extern "C" void kernel_launch(void* const* d_in, const int* in_sizes, int n_in,
                              void* d_out, int out_size, void* d_ws, size_t ws_size,
                              hipStream_t stream) {
  const float* x = (const float*)d_in[0];
  const int* ei = (const int*)d_in[1];
  const float* W1 = (const float*)d_in[2];
  const float* b1 = (const float*)d_in[3];
  const float* W2 = (const float*)d_in[4];
  const float* b2 = (const float*)d_in[5];
  const float* attl = (const float*)d_in[6];
  const float* attr = (const float*)d_in[7];
  float* out = (float*)d_out;

  const int nN = in_sizes[0] / F_IN;
  const int nE = in_sizes[1] / 2;
  const int* src = ei;
  const int* dst = ei + nE;

  char* w = (char*)d_ws;
  size_t off = 0;
  auto alloc = [&](size_t bytes) {
    void* p = (void*)(w + off);
    off = (off + bytes + 255) & ~(size_t)255;
    return p;
  };
  float* raw = (float*)alloc((size_t)nN * HDIM * 4);
  unsigned short* h0 = (unsigned short*)alloc((size_t)nN * HDIM * 2);
  unsigned short* hA = (unsigned short*)alloc((size_t)nN * HDIM * 2);
  unsigned short* hB = (unsigned short*)alloc((size_t)nN * HDIM * 2);
  float2* P = (float2*)alloc((size_t)nN * 8);
  float2* Q = (float2*)alloc((size_t)nN * 8);
  float* selfc = (float*)alloc((size_t)nN * 4);
  float* dinv = (float*)alloc((size_t)nN * 4);
  int* indeg = (int*)alloc((size_t)nN * 4);
  int* fill = (int*)alloc((size_t)nN * 4);
  int* rowptr = (int*)alloc((size_t)(nN + 1) * 4);
  int* csrsrc = (int*)alloc((size_t)nE * 4);
  int* csrdst = (int*)alloc((size_t)nE * 4);
  int2* esc = (int2*)alloc((size_t)nE * 8);
  int* bsum = (int*)alloc(1024);
  int* bpre = (int*)alloc(1024);

  const int nb_n = (nN + 255) / 256;
  const int nb_e = (nE + 255) / 256;
  const int nblk = (nN + 511) / 512;  // <= 128
  const int nb4 = (nN + 3) / 4;

  k_init_n<<<nb_n, 256, 0, stream>>>(indeg, fill, nN);
  k_hist<<<nb_e, 256, 0, stream>>>(dst, indeg, nE);
  k_dinv<<<nb_n, 256, 0, stream>>>(indeg, dinv, nN);
  k_bsum<<<nblk, 256, 0, stream>>>(indeg, bsum, nN);
  k_bscan<<<1, 128, 0, stream>>>(bsum, bpre, rowptr, nblk, nN, nE);
  k_rowptr<<<nblk, 512, 0, stream>>>(indeg, bpre, rowptr, nN);
  k_scatter<<<nb_e, 256, 0, stream>>>(src, dst, rowptr, fill, csrsrc, csrdst, nE);
  k_lin1<<<(nN + 63) / 64, 256, 0, stream>>>(x, W1, b1, raw, nN);
  k_scores<<<nb4, 256, 0, stream>>>(raw, attl, attr, dinv, P, Q, selfc, h0, nN);

  const unsigned short* hin = h0;
  unsigned short* hout = hA;
  for (int l = 0; l < NLAYER; ++l) {
    k_coef<<<nb_e, 256, 0, stream>>>(csrsrc, csrdst, P, Q, esc, nE);
    if (l < NLAYER - 1) {
      k_agg<true><<<nb4, 256, 0, stream>>>(hin, raw, rowptr, esc, dinv, selfc,
                                           attl + (l + 1) * HDIM, attr + (l + 1) * HDIM,
                                           P, Q, hout, nN);
    } else {
      k_agg<false><<<nb4, 256, 0, stream>>>(hin, raw, rowptr, esc, dinv, selfc,
                                            nullptr, nullptr, P, Q, hout, nN);
    }
    hin = hout;
    hout = (hout == hA) ? hB : hA;
  }
  k_out<<<nb4, 256, 0, stream>>>(hin, W2, b2, out, nN);
}

// Round 6
// 309.213 us; speedup vs baseline: 2.2235x; 1.1457x over previous
//
#include <hip/hip_runtime.h>

#define F_IN 512
#define HDIM 64
#define NCLS 40
#define NLAYER 4
#define EPS_F 0.2f

typedef __attribute__((ext_vector_type(8))) short short8;
typedef __attribute__((ext_vector_type(4))) float f32x4;
typedef __attribute__((ext_vector_type(8))) unsigned short ushort8;

__device__ __forceinline__ unsigned short f2bf(float f) {
  unsigned u = __float_as_uint(f);
  u += 0x7FFFu + ((u >> 16) & 1u);  // RNE
  return (unsigned short)(u >> 16);
}
__device__ __forceinline__ float bf2f(unsigned short s) {
  return __uint_as_float(((unsigned)s) << 16);
}

__device__ __forceinline__ float wsum(float v) {
#pragma unroll
  for (int off = 32; off > 0; off >>= 1) v += __shfl_xor(v, off, 64);
  return v;
}

// ---------------- CSR build ----------------
__global__ __launch_bounds__(256) void k_init_n(int* indeg, int* fill, int nN) {
  int i = blockIdx.x * 256 + threadIdx.x;
  if (i < nN) { indeg[i] = 0; fill[i] = 0; }
}

__global__ __launch_bounds__(256) void k_hist(const int* __restrict__ dst, int* indeg, int nE) {
  int e = blockIdx.x * 256 + threadIdx.x;
  if (e < nE) atomicAdd(&indeg[dst[e]], 1);
}

__global__ __launch_bounds__(256) void k_dinv(const int* __restrict__ indeg, float* dinv, int nN) {
  int i = blockIdx.x * 256 + threadIdx.x;
  if (i < nN) dinv[i] = rsqrtf((float)indeg[i] + 1.0f);  // +1 self-loop
}

__global__ __launch_bounds__(256) void k_bsum(const int* __restrict__ indeg, int* bsum, int nN) {
  int i0 = blockIdx.x * 512 + threadIdx.x;
  int v = 0;
  if (i0 < nN) v += indeg[i0];
  if (i0 + 256 < nN) v += indeg[i0 + 256];
#pragma unroll
  for (int off = 32; off > 0; off >>= 1) v += __shfl_xor(v, off, 64);
  __shared__ int s[4];
  if ((threadIdx.x & 63) == 0) s[threadIdx.x >> 6] = v;
  __syncthreads();
  if (threadIdx.x == 0) bsum[blockIdx.x] = s[0] + s[1] + s[2] + s[3];
}

__global__ __launch_bounds__(128) void k_bscan(const int* __restrict__ bsum, int* bpre,
                                               int* rowptr, int nblk, int nN, int nE) {
  __shared__ int sb[128];
  int t = threadIdx.x;
  int v = (t < nblk) ? bsum[t] : 0;
  sb[t] = v;
  __syncthreads();
  int acc = v;
  for (int off = 1; off < 128; off <<= 1) {
    int o = (t >= off) ? sb[t - off] : 0;
    __syncthreads();
    acc += o;
    sb[t] = acc;
    __syncthreads();
  }
  if (t < nblk) bpre[t] = acc - v;
  if (t == 0) rowptr[nN] = nE;
}

__global__ __launch_bounds__(512) void k_rowptr(const int* __restrict__ indeg,
                                                const int* __restrict__ bpre, int* rowptr, int nN) {
  __shared__ int sb[512];
  int t = threadIdx.x;
  int i = blockIdx.x * 512 + t;
  int v = (i < nN) ? indeg[i] : 0;
  sb[t] = v;
  __syncthreads();
  int acc = v;
  for (int off = 1; off < 512; off <<= 1) {
    int o = (t >= off) ? sb[t - off] : 0;
    __syncthreads();
    acc += o;
    sb[t] = acc;
    __syncthreads();
  }
  if (i < nN) rowptr[i] = bpre[blockIdx.x] + acc - v;
}

__global__ __launch_bounds__(256) void k_scatter(const int* __restrict__ src,
                                                 const int* __restrict__ dst,
                                                 const int* __restrict__ rowptr, int* fill,
                                                 int* csrsrc, int* csrdst, int nE) {
  int e = blockIdx.x * 256 + threadIdx.x;
  if (e < nE) {
    int d = dst[e];
    int p = atomicAdd(&fill[d], 1);
    int q = rowptr[d] + p;
    csrsrc[q] = src[e];
    csrdst[q] = d;
  }
}

// ---------------- lin1: raw = relu(x @ W1^T + b1) via bf16 MFMA ----------------
__global__ __launch_bounds__(256) void k_lin1(const float* __restrict__ x,
                                              const float* __restrict__ W1,
                                              const float* __restrict__ b1,
                                              float* __restrict__ raw, int nN) {
  __shared__ unsigned short xs[64 * 64];
  __shared__ unsigned short ws[64 * 64];
  const int t = threadIdx.x;
  const int wv = t >> 6;
  const int l = t & 63;
  const int n0 = blockIdx.x * 64;
  const int srow = t >> 2;
  const int sk4 = (t & 3) * 4;
  const bool xvalid = (n0 + srow) < nN;
  const float4* x4 = reinterpret_cast<const float4*>(x);
  const float4* w4 = reinterpret_cast<const float4*>(W1);
  short8* xs8 = reinterpret_cast<short8*>(xs);
  short8* ws8 = reinterpret_cast<short8*>(ws);
  const int wslot0 = srow * 8 + (((t & 3) * 2 + 0) ^ (srow & 7));
  const int wslot1 = srow * 8 + (((t & 3) * 2 + 1) ^ (srow & 7));
  const int arow = l & 15;
  const int kgrp = l >> 4;
  f32x4 acc[4] = {{0.f, 0.f, 0.f, 0.f},
                  {0.f, 0.f, 0.f, 0.f},
                  {0.f, 0.f, 0.f, 0.f},
                  {0.f, 0.f, 0.f, 0.f}};
  float4 xa[4], wa[4];
  {
    const size_t xb = (size_t)(n0 + srow) * (F_IN / 4) + sk4;
    const size_t wb = (size_t)srow * (F_IN / 4) + sk4;
#pragma unroll
    for (int r = 0; r < 4; ++r) {
      xa[r] = xvalid ? x4[xb + r] : make_float4(0.f, 0.f, 0.f, 0.f);
      wa[r] = w4[wb + r];
    }
  }
  for (int c = 0; c < 8; ++c) {
    short8 p0, p1, q0, q1;
    p0[0] = (short)f2bf(xa[0].x); p0[1] = (short)f2bf(xa[0].y);
    p0[2] = (short)f2bf(xa[0].z); p0[3] = (short)f2bf(xa[0].w);
    p0[4] = (short)f2bf(xa[1].x); p0[5] = (short)f2bf(xa[1].y);
    p0[6] = (short)f2bf(xa[1].z); p0[7] = (short)f2bf(xa[1].w);
    p1[0] = (short)f2bf(xa[2].x); p1[1] = (short)f2bf(xa[2].y);
    p1[2] = (short)f2bf(xa[2].z); p1[3] = (short)f2bf(xa[2].w);
    p1[4] = (short)f2bf(xa[3].x); p1[5] = (short)f2bf(xa[3].y);
    p1[6] = (short)f2bf(xa[3].z); p1[7] = (short)f2bf(xa[3].w);
    q0[0] = (short)f2bf(wa[0].x); q0[1] = (short)f2bf(wa[0].y);
    q0[2] = (short)f2bf(wa[0].z); q0[3] = (short)f2bf(wa[0].w);
    q0[4] = (short)f2bf(wa[1].x); q0[5] = (short)f2bf(wa[1].y);
    q0[6] = (short)f2bf(wa[1].z); q0[7] = (short)f2bf(wa[1].w);
    q1[0] = (short)f2bf(wa[2].x); q1[1] = (short)f2bf(wa[2].y);
    q1[2] = (short)f2bf(wa[2].z); q1[3] = (short)f2bf(wa[2].w);
    q1[4] = (short)f2bf(wa[3].x); q1[5] = (short)f2bf(wa[3].y);
    q1[6] = (short)f2bf(wa[3].z); q1[7] = (short)f2bf(wa[3].w);
    xs8[wslot0] = p0;
    xs8[wslot1] = p1;
    ws8[wslot0] = q0;
    ws8[wslot1] = q1;
    __syncthreads();
    if (c < 7) {
      const size_t xb = (size_t)(n0 + srow) * (F_IN / 4) + (c + 1) * 16 + sk4;
      const size_t wb = (size_t)srow * (F_IN / 4) + (c + 1) * 16 + sk4;
#pragma unroll
      for (int r = 0; r < 4; ++r) {
        xa[r] = xvalid ? x4[xb + r] : make_float4(0.f, 0.f, 0.f, 0.f);
        wa[r] = w4[wb + r];
      }
    }
#pragma unroll
    for (int c2 = 0; c2 < 2; ++c2) {
      const short8 a = xs8[(wv * 16 + arow) * 8 + ((c2 * 4 + kgrp) ^ (arow & 7))];
#pragma unroll
      for (int fs = 0; fs < 4; ++fs) {
        const short8 b = ws8[(fs * 16 + arow) * 8 + ((c2 * 4 + kgrp) ^ (arow & 7))];
        acc[fs] = __builtin_amdgcn_mfma_f32_16x16x32_bf16(a, b, acc[fs], 0, 0, 0);
      }
    }
    __syncthreads();
  }
#pragma unroll
  for (int fs = 0; fs < 4; ++fs) {
    const int feat = fs * 16 + arow;
    const float bias = b1[feat];
#pragma unroll
    for (int j = 0; j < 4; ++j) {
      const int node = n0 + wv * 16 + kgrp * 4 + j;
      if (node < nN) raw[(size_t)node * HDIM + feat] = fmaxf(acc[fs][j] + bias, 0.f);
    }
  }
}

// ---------------- layer-0 scores + bf16 copy of raw ----------------
__global__ __launch_bounds__(256) void k_scores(const float* __restrict__ raw,
                                                const float* __restrict__ attl,
                                                const float* __restrict__ attr,
                                                const float* __restrict__ dinv,
                                                float2* __restrict__ P, float2* __restrict__ Q,
                                                float* __restrict__ selfc,
                                                unsigned short* __restrict__ h0, int nN) {
  int wid = threadIdx.x >> 6, lane = threadIdx.x & 63;
  int n = blockIdx.x * 4 + wid;
  if (n >= nN) return;
  float v = raw[(size_t)n * HDIM + lane];
  h0[(size_t)n * HDIM + lane] = f2bf(v);
  float sl = wsum(v * attl[lane]);
  float sr = wsum(v * attr[lane]);
  if (lane == 0) {
    float dv = dinv[n];
    P[n] = make_float2(sl, dv);
    Q[n] = make_float2(sr, dv);
    selfc[n] = tanhf(sl + sr) * dv * dv;
  }
}

// ---------------- per-layer edge coefficients ----------------
__global__ __launch_bounds__(256) void k_coef(const int* __restrict__ csrsrc,
                                              const int* __restrict__ csrdst,
                                              const float2* __restrict__ P,
                                              const float2* __restrict__ Q,
                                              int2* __restrict__ esc, int nE) {
  int e = blockIdx.x * 256 + threadIdx.x;
  if (e < nE) {
    int s = csrsrc[e], d = csrdst[e];
    float2 p = P[s], q = Q[d];
    float c = tanhf(p.x + q.x) * (p.y * q.y);
    esc[e] = make_int2(s, __float_as_int(c));
  }
}

// ---------------- aggregation: wave/dest, 8 edge-groups x 8 lanes, bf16 gathers ----------------
template <bool WNEXT>
__global__ __launch_bounds__(256) void k_agg(const unsigned short* __restrict__ h,
                                             const float* __restrict__ raw,
                                             const int* __restrict__ rowptr,
                                             const int2* __restrict__ esc,
                                             const float* __restrict__ dinv,
                                             float* __restrict__ selfc,
                                             const float* __restrict__ attl_n,
                                             const float* __restrict__ attr_n,
                                             float2* __restrict__ P, float2* __restrict__ Q,
                                             unsigned short* __restrict__ hout, int nN) {
  const int wid = threadIdx.x >> 6, lane = threadIdx.x & 63;
  const int d = blockIdx.x * 4 + wid;
  if (d >= nN) return;
  const int grp = lane >> 3;
  const int fo = (lane & 7) * 8;
  const size_t base = (size_t)d * HDIM + fo;
  float acc[8] = {};
  if (grp == 0) {
    const float sc = selfc[d];
    const ushort8 hd = *reinterpret_cast<const ushort8*>(&h[base]);
    const float4 r0 = *reinterpret_cast<const float4*>(&raw[base]);
    const float4 r1 = *reinterpret_cast<const float4*>(&raw[base + 4]);
    acc[0] = fmaf(bf2f(hd[0]), sc, EPS_F * r0.x);
    acc[1] = fmaf(bf2f(hd[1]), sc, EPS_F * r0.y);
    acc[2] = fmaf(bf2f(hd[2]), sc, EPS_F * r0.z);
    acc[3] = fmaf(bf2f(hd[3]), sc, EPS_F * r0.w);
    acc[4] = fmaf(bf2f(hd[4]), sc, EPS_F * r1.x);
    acc[5] = fmaf(bf2f(hd[5]), sc, EPS_F * r1.y);
    acc[6] = fmaf(bf2f(hd[6]), sc, EPS_F * r1.z);
    acc[7] = fmaf(bf2f(hd[7]), sc, EPS_F * r1.w);
  }
  const int e1 = rowptr[d + 1];
  int e = rowptr[d] + grp;
  for (; e + 8 < e1; e += 16) {
    const int2 v0 = esc[e];
    const int2 v1 = esc[e + 8];
    const ushort8 h0v = *reinterpret_cast<const ushort8*>(&h[(size_t)v0.x * HDIM + fo]);
    const ushort8 h1v = *reinterpret_cast<const ushort8*>(&h[(size_t)v1.x * HDIM + fo]);
    const float c0 = __int_as_float(v0.y);
    const float c1 = __int_as_float(v1.y);
#pragma unroll
    for (int j = 0; j < 8; ++j) acc[j] = fmaf(bf2f(h0v[j]), c0, acc[j]);
#pragma unroll
    for (int j = 0; j < 8; ++j) acc[j] = fmaf(bf2f(h1v[j]), c1, acc[j]);
  }
  for (; e < e1; e += 8) {
    const int2 v = esc[e];
    const ushort8 hv = *reinterpret_cast<const ushort8*>(&h[(size_t)v.x * HDIM + fo]);
    const float c = __int_as_float(v.y);
#pragma unroll
    for (int j = 0; j < 8; ++j) acc[j] = fmaf(bf2f(hv[j]), c, acc[j]);
  }
#pragma unroll
  for (int off = 8; off <= 32; off <<= 1) {
#pragma unroll
    for (int j = 0; j < 8; ++j) acc[j] += __shfl_xor(acc[j], off, 64);
  }
  if (grp == 0) {
    ushort8 o;
#pragma unroll
    for (int j = 0; j < 8; ++j) o[j] = f2bf(acc[j]);
    *reinterpret_cast<ushort8*>(&hout[base]) = o;
  }
  if (WNEXT) {
    const float4 al0 = *reinterpret_cast<const float4*>(&attl_n[fo]);
    const float4 al1 = *reinterpret_cast<const float4*>(&attl_n[fo + 4]);
    const float4 ar0 = *reinterpret_cast<const float4*>(&attr_n[fo]);
    const float4 ar1 = *reinterpret_cast<const float4*>(&attr_n[fo + 4]);
    float psl = acc[0] * al0.x + acc[1] * al0.y + acc[2] * al0.z + acc[3] * al0.w +
                acc[4] * al1.x + acc[5] * al1.y + acc[6] * al1.z + acc[7] * al1.w;
    float psr = acc[0] * ar0.x + acc[1] * ar0.y + acc[2] * ar0.z + acc[3] * ar0.w +
                acc[4] * ar1.x + acc[5] * ar1.y + acc[6] * ar1.z + acc[7] * ar1.w;
#pragma unroll
    for (int off = 1; off <= 4; off <<= 1) {
      psl += __shfl_xor(psl, off, 64);
      psr += __shfl_xor(psr, off, 64);
    }
    if (lane == 0) {
      const float dv = dinv[d];
      P[d] = make_float2(psl, dv);
      Q[d] = make_float2(psr, dv);
      selfc[d] = tanhf(psl + psr) * dv * dv;
    }
  }
}

// ---------------- output: thread-per-node logits + log_softmax ----------------
// W2 staged [c][j] in LDS; inner reads are wave-uniform float4 broadcasts (no conflicts).
// h row register-resident (bf16 -> f32).
__global__ __launch_bounds__(256) void k_out(const unsigned short* __restrict__ h,
                                             const float* __restrict__ W2,
                                             const float* __restrict__ b2,
                                             float* __restrict__ out, int nN) {
  __shared__ float w2s[NCLS * HDIM];  // [c][j] row-major (same as W2)
  __shared__ float b2s[NCLS];
  for (int i = threadIdx.x; i < NCLS * HDIM; i += 256) w2s[i] = W2[i];
  if (threadIdx.x < NCLS) b2s[threadIdx.x] = b2[threadIdx.x];
  __syncthreads();
  const int n = blockIdx.x * 256 + threadIdx.x;
  if (n >= nN) return;
  // load h row into registers
  float hr[HDIM];
  const ushort8* hrow = reinterpret_cast<const ushort8*>(&h[(size_t)n * HDIM]);
#pragma unroll
  for (int r = 0; r < 8; ++r) {
    const ushort8 v = hrow[r];
#pragma unroll
    for (int j = 0; j < 8; ++j) hr[r * 8 + j] = bf2f(v[j]);
  }
  const float4* w2s4 = reinterpret_cast<const float4*>(w2s);
  float logits[NCLS];
  float m = -INFINITY;
#pragma unroll
  for (int c = 0; c < NCLS; ++c) {
    float a0 = 0.f, a1 = 0.f, a2 = 0.f, a3 = 0.f;
#pragma unroll
    for (int j4 = 0; j4 < HDIM / 4; j4 += 4) {
      const float4 w0 = w2s4[c * (HDIM / 4) + j4 + 0];
      const float4 w1 = w2s4[c * (HDIM / 4) + j4 + 1];
      const float4 w2v = w2s4[c * (HDIM / 4) + j4 + 2];
      const float4 w3 = w2s4[c * (HDIM / 4) + j4 + 3];
      const int j = j4 * 4;
      a0 = fmaf(hr[j + 0], w0.x, a0);  a0 = fmaf(hr[j + 1], w0.y, a0);
      a0 = fmaf(hr[j + 2], w0.z, a0);  a0 = fmaf(hr[j + 3], w0.w, a0);
      a1 = fmaf(hr[j + 4], w1.x, a1);  a1 = fmaf(hr[j + 5], w1.y, a1);
      a1 = fmaf(hr[j + 6], w1.z, a1);  a1 = fmaf(hr[j + 7], w1.w, a1);
      a2 = fmaf(hr[j + 8], w2v.x, a2); a2 = fmaf(hr[j + 9], w2v.y, a2);
      a2 = fmaf(hr[j + 10], w2v.z, a2); a2 = fmaf(hr[j + 11], w2v.w, a2);
      a3 = fmaf(hr[j + 12], w3.x, a3); a3 = fmaf(hr[j + 13], w3.y, a3);
      a3 = fmaf(hr[j + 14], w3.z, a3); a3 = fmaf(hr[j + 15], w3.w, a3);
    }
    const float lg = (a0 + a1) + (a2 + a3) + b2s[c];
    logits[c] = lg;
    m = fmaxf(m, lg);
  }
  float s = 0.f;
#pragma unroll
  for (int c = 0; c < NCLS; ++c) s += expf(logits[c] - m);
  const float lse = m + logf(s);
  float4* o4 = reinterpret_cast<float4*>(&out[(size_t)n * NCLS]);
#pragma unroll
  for (int c4 = 0; c4 < NCLS / 4; ++c4) {
    float4 o;
    o.x = logits[c4 * 4 + 0] - lse;
    o.y = logits[c4 * 4 + 1] - lse;
    o.z = logits[c4 * 4 + 2] - lse;
    o.w = logits[c4 * 4 + 3] - lse;
    o4[c4] = o;
  }
}

extern "C" void kernel_launch(void* const* d_in, const int* in_sizes, int n_in,
                              void* d_out, int out_size, void* d_ws, size_t ws_size,
                              hipStream_t stream) {
  const float* x = (const float*)d_in[0];
  const int* ei = (const int*)d_in[1];
  const float* W1 = (const float*)d_in[2];
  const float* b1 = (const float*)d_in[3];
  const float* W2 = (const float*)d_in[4];
  const float* b2 = (const float*)d_in[5];
  const float* attl = (const float*)d_in[6];
  const float* attr = (const float*)d_in[7];
  float* out = (float*)d_out;

  const int nN = in_sizes[0] / F_IN;
  const int nE = in_sizes[1] / 2;
  const int* src = ei;
  const int* dst = ei + nE;

  char* w = (char*)d_ws;
  size_t off = 0;
  auto alloc = [&](size_t bytes) {
    void* p = (void*)(w + off);
    off = (off + bytes + 255) & ~(size_t)255;
    return p;
  };
  float* raw = (float*)alloc((size_t)nN * HDIM * 4);
  unsigned short* h0 = (unsigned short*)alloc((size_t)nN * HDIM * 2);
  unsigned short* hA = (unsigned short*)alloc((size_t)nN * HDIM * 2);
  unsigned short* hB = (unsigned short*)alloc((size_t)nN * HDIM * 2);
  float2* P = (float2*)alloc((size_t)nN * 8);
  float2* Q = (float2*)alloc((size_t)nN * 8);
  float* selfc = (float*)alloc((size_t)nN * 4);
  float* dinv = (float*)alloc((size_t)nN * 4);
  int* indeg = (int*)alloc((size_t)nN * 4);
  int* fill = (int*)alloc((size_t)nN * 4);
  int* rowptr = (int*)alloc((size_t)(nN + 1) * 4);
  int* csrsrc = (int*)alloc((size_t)nE * 4);
  int* csrdst = (int*)alloc((size_t)nE * 4);
  int2* esc = (int2*)alloc((size_t)nE * 8);
  int* bsum = (int*)alloc(1024);
  int* bpre = (int*)alloc(1024);

  const int nb_n = (nN + 255) / 256;
  const int nb_e = (nE + 255) / 256;
  const int nblk = (nN + 511) / 512;  // <= 128
  const int nb4 = (nN + 3) / 4;

  k_init_n<<<nb_n, 256, 0, stream>>>(indeg, fill, nN);
  k_hist<<<nb_e, 256, 0, stream>>>(dst, indeg, nE);
  k_dinv<<<nb_n, 256, 0, stream>>>(indeg, dinv, nN);
  k_bsum<<<nblk, 256, 0, stream>>>(indeg, bsum, nN);
  k_bscan<<<1, 128, 0, stream>>>(bsum, bpre, rowptr, nblk, nN, nE);
  k_rowptr<<<nblk, 512, 0, stream>>>(indeg, bpre, rowptr, nN);
  k_scatter<<<nb_e, 256, 0, stream>>>(src, dst, rowptr, fill, csrsrc, csrdst, nE);
  k_lin1<<<(nN + 63) / 64, 256, 0, stream>>>(x, W1, b1, raw, nN);
  k_scores<<<nb4, 256, 0, stream>>>(raw, attl, attr, dinv, P, Q, selfc, h0, nN);

  const unsigned short* hin = h0;
  unsigned short* hout = hA;
  for (int l = 0; l < NLAYER; ++l) {
    k_coef<<<nb_e, 256, 0, stream>>>(csrsrc, csrdst, P, Q, esc, nE);
    if (l < NLAYER - 1) {
      k_agg<true><<<nb4, 256, 0, stream>>>(hin, raw, rowptr, esc, dinv, selfc,
                                           attl + (l + 1) * HDIM, attr + (l + 1) * HDIM,
                                           P, Q, hout, nN);
    } else {
      k_agg<false><<<nb4, 256, 0, stream>>>(hin, raw, rowptr, esc, dinv, selfc,
                                            nullptr, nullptr, P, Q, hout, nN);
    }
    hin = hout;
    hout = (hout == hA) ? hB : hA;
  }
  k_out<<<nb_n, 256, 0, stream>>>(hin, W2, b2, out, nN);
}